// Round 1
// baseline (188.072 us; speedup 1.0000x reference)
//
#include <hip/hip_runtime.h>
#include <hip/hip_bf16.h>
#include <math.h>

#define NN 4096      // nodes
#define C  256       // feature dim
#define NH 8         // heads
#define HD 32        // head dim
#define LN_EPS 1e-5f
#define LOG2E 1.44269504088896340736f

typedef unsigned short u16;
typedef __attribute__((ext_vector_type(8))) short bf16x8;
typedef __attribute__((ext_vector_type(4))) float f32x4;
typedef __attribute__((ext_vector_type(16))) float f32x16;

__device__ inline u16 f2b(float f) {
    union { float f; unsigned u; } v; v.f = f;
    unsigned r = (v.u + 0x7fff + ((v.u >> 16) & 1)) >> 16;  // RNE
    return (u16)r;
}

__device__ inline float fexp2(float x) {
#if __has_builtin(__builtin_amdgcn_exp2f)
    return __builtin_amdgcn_exp2f(x);      // single v_exp_f32
#else
    return exp2f(x);
#endif
}

// pack bf16(e0)|bf16(e1)<<16 by truncation: ONE v_perm_b32
__device__ inline unsigned pack_trunc(float e0, float e1) {
    return __builtin_amdgcn_perm(__float_as_uint(e1), __float_as_uint(e0),
                                 0x07060302u);
}

__device__ inline void atomic_add_agent(float* p, float v) {
    __hip_atomic_fetch_add(p, v, __ATOMIC_RELAXED, __HIP_MEMORY_SCOPE_AGENT);
}

// ---------------------------------------------------------------------------
// Kernel 0: prep — z<4: weight transpose+bf16 (WqkvT=[Wq^T|Wk^T|Wv^T], WoT);
// z>=4: x fp32->bf16 slice conversion (fused to save a dispatch).
// grid (8,8,8), block 256.
// ---------------------------------------------------------------------------
__global__ __launch_bounds__(256) void prep_kernel(
    const float* __restrict__ Wq, const float* __restrict__ Wk,
    const float* __restrict__ Wv, const float* __restrict__ Wo,
    const float* __restrict__ x,
    u16* __restrict__ WqkvT, u16* __restrict__ WoT, u16* __restrict__ xb)
{
    const int z = blockIdx.z;
    if (z < 4) {
        __shared__ float tile[32][33];
        const float* W = (z == 0) ? Wq : (z == 1) ? Wk : (z == 2) ? Wv : Wo;
        u16* WT = (z == 3) ? WoT : (WqkvT + (size_t)z * 256 * 256);
        const int tx = threadIdx.x & 31, ty = threadIdx.x >> 5;
        const int n0 = blockIdx.x * 32, k0 = blockIdx.y * 32;
        #pragma unroll
        for (int i = 0; i < 32; i += 8)
            tile[ty + i][tx] = W[(size_t)(k0 + ty + i) * 256 + n0 + tx];
        __syncthreads();
        #pragma unroll
        for (int i = 0; i < 32; i += 8)
            WT[(size_t)(n0 + ty + i) * 256 + k0 + tx] = f2b(tile[tx][ty + i]);
    } else {
        // x conversion: 4 slices x 64 blocks x 256 thr x 16 elems = NN*C
        const int slice = z - 4;
        const int bid = blockIdx.x * 8 + blockIdx.y;
        const int base = slice * (NN * C / 4) + bid * 4096 + threadIdx.x * 16;
        #pragma unroll
        for (int i = 0; i < 4; ++i) {
            const float4 v = *(const float4*)(x + base + i * 4);
            union { u16 u[4]; unsigned long long ull; } pk;
            pk.u[0] = f2b(v.x); pk.u[1] = f2b(v.y);
            pk.u[2] = f2b(v.z); pk.u[3] = f2b(v.w);
            *(unsigned long long*)(xb + base + i * 4) = pk.ull;
        }
    }
}

// ---------------------------------------------------------------------------
// Kernel 1: QKV projection via MFMA (64x64 tiles, 4 waves). A-frag is a
// single 16B load from pre-converted xb. qb pre-scaled by scale*log2e;
// v emitted as V^T.
// ---------------------------------------------------------------------------
__global__ __launch_bounds__(256) void qkv_mfma_kernel(
    const u16* __restrict__ xb, const u16* __restrict__ WT,
    const float* __restrict__ bq, const float* __restrict__ bk,
    const float* __restrict__ bv, const float* __restrict__ scale_p,
    u16* __restrict__ qb, u16* __restrict__ kb, u16* __restrict__ vT)
{
    const int m0 = blockIdx.x * 64;
    const int n0 = blockIdx.y * 64;
    const int t = threadIdx.x;
    const int wave = t >> 6, lane = t & 63;
    const int l16 = lane & 15, quad = lane >> 4;

    f32x4 acc[4];
    #pragma unroll
    for (int ct = 0; ct < 4; ++ct) acc[ct] = f32x4{0.f, 0.f, 0.f, 0.f};

    const u16* xrow = xb + (size_t)(m0 + wave * 16 + l16) * C;
    #pragma unroll
    for (int kk = 0; kk < 8; ++kk) {
        const bf16x8 af = *(const bf16x8*)(xrow + kk * 32 + quad * 8);
        #pragma unroll
        for (int ct = 0; ct < 4; ++ct) {
            const bf16x8 bfr = *(const bf16x8*)(
                WT + (size_t)(n0 + ct * 16 + l16) * C + kk * 32 + quad * 8);
            acc[ct] = __builtin_amdgcn_mfma_f32_16x16x32_bf16(af, bfr, acc[ct], 0, 0, 0);
        }
    }

    const int sect = n0 >> 8;
    const int c0 = n0 & 255;
    const int rbase = m0 + wave * 16 + quad * 4;
    if (sect == 0) {
        const float scl = (*scale_p) * LOG2E;
        #pragma unroll
        for (int ct = 0; ct < 4; ++ct) {
            const int c = c0 + ct * 16 + l16;
            const float b = bq[c];
            #pragma unroll
            for (int r = 0; r < 4; ++r)
                qb[(size_t)(rbase + r) * C + c] = f2b((acc[ct][r] + b) * scl);
        }
    } else if (sect == 1) {
        #pragma unroll
        for (int ct = 0; ct < 4; ++ct) {
            const int c = c0 + ct * 16 + l16;
            const float b = bk[c];
            #pragma unroll
            for (int r = 0; r < 4; ++r)
                kb[(size_t)(rbase + r) * C + c] = f2b(acc[ct][r] + b);
        }
    } else {
        #pragma unroll
        for (int ct = 0; ct < 4; ++ct) {
            const int c = c0 + ct * 16 + l16;
            const float b = bv[c];
            union { u16 u[4]; unsigned long long ull; } pk;
            #pragma unroll
            for (int r = 0; r < 4; ++r) pk.u[r] = f2b(acc[ct][r] + b);
            *(unsigned long long*)(vT + (size_t)c * NN + rbase) = pk.ull;
        }
    }
}

// ---------------------------------------------------------------------------
// Kernel 2: MFMA attention, LDS-FREE. 32x32x16 MFMAs, swapped QK^T so each
// lane owns P[q=lane&31][j=crow(r,hi)]; P->PV A-frag built in-register via
// pack_trunc + v_permlane32_swap (2 swaps per 16-j chunk). K and V fragments
// are read directly from global in MFMA layout (16B/lane); per-(h,z) K/V
// slice (128KB) is pinned to one XCD's L2 via flat-id swizzle. No __shared__,
// no barriers. Unnormalized O and l accumulate via agent-scope fp32 atomics.
// ---------------------------------------------------------------------------
#define NZ 4
#define ZT (NN / NZ)       // 1024 keys per z-slice
#define NIT (ZT / 32)      // 32 j-tiles of 32 keys

__global__ __launch_bounds__(256, 4) void attn_mfma_kernel(
    const u16* __restrict__ q, const u16* __restrict__ k,
    const u16* __restrict__ vT, float* __restrict__ msgacc,
    float* __restrict__ lacc)
{
    // flat-id -> (qb, h, z) swizzle: blocks sharing an (h,z) K/V slice land
    // on the same XCD (flat ids congruent mod 8) for L2 residency.
    const int fid = blockIdx.x + 32 * (blockIdx.y + 8 * blockIdx.z); // 0..1023
    const int qb  = (fid >> 3) & 31;
    const int sl  = (fid & 7) + 8 * (fid >> 8);   // 0..31 slice id
    const int h = sl & 7, z = sl >> 3;

    const int t = threadIdx.x;
    const int wave = t >> 6, lane = t & 63;
    const int l31 = lane & 31, hi = lane >> 5;
    const int qbase = qb * 128 + wave * 32;       // 32 q-rows per wave

    // Q as MFMA B-operand: lane holds Q[q=qbase+l31][d = hi*8 + e (+16)]
    const u16* qrp = q + (size_t)(qbase + l31) * C + h * HD + hi * 8;
    const bf16x8 qf0 = *(const bf16x8*)(qrp);        // d 0..15
    const bf16x8 qf1 = *(const bf16x8*)(qrp + 16);   // d 16..31

    f32x16 o = {0.f,0.f,0.f,0.f, 0.f,0.f,0.f,0.f,
                0.f,0.f,0.f,0.f, 0.f,0.f,0.f,0.f};   // O[q=crow(r,hi)][d=l31]
    float lsum = 0.f;

    // K A-frag rows: lane reads K[j = jbase + l31][d = hi*8 + e (+16)]
    const u16* k0p = k + (size_t)(z * ZT + l31) * C + h * HD + hi * 8;
    // V B-frag: lane reads vT[d = l31][j = jbase + hi*8 + e (+16)]
    const u16* v0p = vT + (size_t)(h * HD + l31) * NN + z * ZT + hi * 8;

    const u16* kp = k0p;
    const u16* vp = v0p;
    bf16x8 kf0 = *(const bf16x8*)(kp);
    bf16x8 kf1 = *(const bf16x8*)(kp + 16);

    for (int it = 0; it < NIT; ++it) {
        // prefetch next K tile (wrap to tile 0 on last iter; always valid)
        const u16* kpn = (it + 1 < NIT) ? kp + 32 * C : k0p;
        const bf16x8 kf0n = *(const bf16x8*)(kpn);
        const bf16x8 kf1n = *(const bf16x8*)(kpn + 16);
        // V for current tile: needed only after QK+exp, latency covered
        const bf16x8 vf0 = *(const bf16x8*)(vp);         // j 0..15 of tile
        const bf16x8 vf1 = *(const bf16x8*)(vp + 16);    // j 16..31

        // S^T[j, q] for 32 j x 32 q, contraction over d=32 in two K=16 steps
        f32x16 s = {0.f,0.f,0.f,0.f, 0.f,0.f,0.f,0.f,
                    0.f,0.f,0.f,0.f, 0.f,0.f,0.f,0.f};
        s = __builtin_amdgcn_mfma_f32_32x32x16_bf16(kf0, qf0, s, 0, 0, 0);
        s = __builtin_amdgcn_mfma_f32_32x32x16_bf16(kf1, qf1, s, 0, 0, 0);

        // Per 16-j chunk: exp2, pack to bf16, permlane32_swap into the PV
        // A-frag (lane needs P[q=l31][j = hi*8+e]), then PV MFMA.
        #pragma unroll
        for (int c = 0; c < 2; ++c) {
            const float e0 = fexp2(s[8 * c + 0]);
            const float e1 = fexp2(s[8 * c + 1]);
            const float e2 = fexp2(s[8 * c + 2]);
            const float e3 = fexp2(s[8 * c + 3]);
            const float e4 = fexp2(s[8 * c + 4]);
            const float e5 = fexp2(s[8 * c + 5]);
            const float e6 = fexp2(s[8 * c + 6]);
            const float e7 = fexp2(s[8 * c + 7]);
            lsum += ((e0 + e1) + (e2 + e3)) + ((e4 + e5) + (e6 + e7));
            const unsigned p01 = pack_trunc(e0, e1);
            const unsigned p23 = pack_trunc(e2, e3);
            const unsigned p45 = pack_trunc(e4, e5);
            const unsigned p67 = pack_trunc(e6, e7);
            // swap upper-32-lanes(dst) <-> lower-32-lanes(src):
            //   r[0]: hi=0 own p01 / hi=1 partner p45  -> frag word 0
            //   r[1]: hi=0 partner p01 / hi=1 own p45  -> frag word 2
            const auto w02 = __builtin_amdgcn_permlane32_swap(p01, p45, false, false);
            const auto w13 = __builtin_amdgcn_permlane32_swap(p23, p67, false, false);
            union { unsigned w[4]; bf16x8 v; } pa;
            pa.w[0] = w02[0]; pa.w[1] = w13[0];
            pa.w[2] = w02[1]; pa.w[3] = w13[1];
            o = __builtin_amdgcn_mfma_f32_32x32x16_bf16(
                    pa.v, c ? vf1 : vf0, o, 0, 0, 0);
        }

        kp = kpn; vp += 32;
        kf0 = kf0n; kf1 = kf1n;
    }

    // lsum currently covers this lane's 16 j per tile; partner half has the
    // other 16. One xor-32 completes the row sum for q = qbase + l31.
    lsum += __shfl_xor(lsum, 32);
    if (hi == 0)
        atomic_add_agent(&lacc[(size_t)(qbase + l31) * NH + h], lsum);

    #pragma unroll
    for (int r = 0; r < 16; ++r) {
        const int qr = qbase + (r & 3) + 8 * (r >> 2) + 4 * hi;
        atomic_add_agent(&msgacc[(size_t)qr * C + h * HD + l31], o[r]);
    }
}

// ---------------------------------------------------------------------------
// Kernel 3: y = x + (msgacc/l) @ Wo + bo, LayerNorm. 8-row tiles, 512 blocks.
// MFMA computes 16 rows; rows 8..15 discarded. Row-clamped loads.
// ---------------------------------------------------------------------------
#define OROWS 8
__global__ __launch_bounds__(256) void out_ln_mfma_kernel(
    const float* __restrict__ msgacc, const float* __restrict__ lacc,
    const u16* __restrict__ WoT, const float* __restrict__ bo,
    const float* __restrict__ x, const float* __restrict__ gamma,
    const float* __restrict__ beta, float* __restrict__ out)
{
    __shared__ float sums[2][4][OROWS];
    const int m0 = blockIdx.x * OROWS;
    const int t = threadIdx.x;
    const int w = t >> 6, lane = t & 63;
    const int l16 = lane & 15, quad = lane >> 4;

    f32x4 acc[4];
    #pragma unroll
    for (int ct = 0; ct < 4; ++ct) acc[ct] = f32x4{0.f, 0.f, 0.f, 0.f};

    const int ar = min(m0 + l16, NN - 1);
    const float* arow = msgacc + (size_t)ar * C;
    const float* lrow = lacc + (size_t)ar * NH;
    #pragma unroll
    for (int kk = 0; kk < 8; ++kk) {
        const float li = 1.f / lrow[kk];
        const float4 a0 = *(const float4*)(arow + kk * 32 + quad * 8);
        const float4 a1 = *(const float4*)(arow + kk * 32 + quad * 8 + 4);
        union { __hip_bfloat162 h2[4]; bf16x8 v; } af;
        af.h2[0] = __float22bfloat162_rn(float2{a0.x * li, a0.y * li});
        af.h2[1] = __float22bfloat162_rn(float2{a0.z * li, a0.w * li});
        af.h2[2] = __float22bfloat162_rn(float2{a1.x * li, a1.y * li});
        af.h2[3] = __float22bfloat162_rn(float2{a1.z * li, a1.w * li});
        #pragma unroll
        for (int ct = 0; ct < 4; ++ct) {
            const bf16x8 bfr = *(const bf16x8*)(
                WoT + (size_t)(w * 64 + ct * 16 + l16) * C + kk * 32 + quad * 8);
            acc[ct] = __builtin_amdgcn_mfma_f32_16x16x32_bf16(af.v, bfr, acc[ct], 0, 0, 0);
        }
    }

    float val[4][4];
    if (quad < 2) {
        #pragma unroll
        for (int r = 0; r < 4; ++r) {
            const int row = m0 + quad * 4 + r;
            float sr = 0.f, qr = 0.f;
            #pragma unroll
            for (int ct = 0; ct < 4; ++ct) {
                const int c = w * 64 + ct * 16 + l16;
                const float v = acc[ct][r] + bo[c] + x[(size_t)row * C + c];
                val[ct][r] = v;
                sr += v;
                qr = fmaf(v, v, qr);
            }
            sr += __shfl_xor(sr, 1); sr += __shfl_xor(sr, 2);
            sr += __shfl_xor(sr, 4); sr += __shfl_xor(sr, 8);
            qr += __shfl_xor(qr, 1); qr += __shfl_xor(qr, 2);
            qr += __shfl_xor(qr, 4); qr += __shfl_xor(qr, 8);
            if (l16 == 0) {
                sums[0][w][quad * 4 + r] = sr;
                sums[1][w][quad * 4 + r] = qr;
            }
        }
    }
    __syncthreads();

    if (quad < 2) {
        #pragma unroll
        for (int r = 0; r < 4; ++r) {
            const int ri = quad * 4 + r;
            const int row = m0 + ri;
            const float tot  = sums[0][0][ri] + sums[0][1][ri] + sums[0][2][ri] + sums[0][3][ri];
            const float tot2 = sums[1][0][ri] + sums[1][1][ri] + sums[1][2][ri] + sums[1][3][ri];
            const float mu = tot * (1.f / C);
            const float var = fmaxf(tot2 * (1.f / C) - mu * mu, 0.f);
            const float rstd = rsqrtf(var + LN_EPS);
            #pragma unroll
            for (int ct = 0; ct < 4; ++ct) {
                const int c = w * 64 + ct * 16 + l16;
                out[(size_t)row * C + c] = (val[ct][r] - mu) * rstd * gamma[c] + beta[c];
            }
        }
    }
}

// ---------------------------------------------------------------------------
extern "C" void kernel_launch(void* const* d_in, const int* in_sizes, int n_in,
                              void* d_out, int out_size, void* d_ws, size_t ws_size,
                              hipStream_t stream) {
    const float* x     = (const float*)d_in[0];
    const float* Wq    = (const float*)d_in[1];
    const float* bq    = (const float*)d_in[2];
    const float* Wk    = (const float*)d_in[3];
    const float* bk    = (const float*)d_in[4];
    const float* Wv    = (const float*)d_in[5];
    const float* bv    = (const float*)d_in[6];
    const float* scale = (const float*)d_in[7];
    const float* Wo    = (const float*)d_in[8];
    const float* bo    = (const float*)d_in[9];
    const float* gamma = (const float*)d_in[10];
    const float* beta  = (const float*)d_in[11];
    float* out = (float*)d_out;

    u16* qb     = (u16*)d_ws;                              // 2 MB
    u16* kb     = qb + (size_t)NN * C;                     // 2 MB
    u16* vT     = kb + (size_t)NN * C;                     // 2 MB
    u16* xbuf   = vT + (size_t)NN * C;                     // 2 MB
    u16* WqkvT  = xbuf + (size_t)NN * C;                   // 384 KB
    u16* WoT    = WqkvT + (size_t)3 * C * C;               // 128 KB
    float* msgacc = (float*)(WoT + (size_t)C * C);         // 4 MB
    float* lacc   = msgacc + (size_t)NN * C;               // 128 KB (contiguous)

    hipMemsetAsync(msgacc, 0, ((size_t)NN * C + (size_t)NN * NH) * sizeof(float),
                   stream);

    prep_kernel<<<dim3(8, 8, 8), 256, 0, stream>>>(Wq, Wk, Wv, Wo, x,
                                                   WqkvT, WoT, xbuf);
    qkv_mfma_kernel<<<dim3(NN / 64, 12), 256, 0, stream>>>(
        xbuf, WqkvT, bq, bk, bv, scale, qb, kb, vT);
    attn_mfma_kernel<<<dim3(NN / 128, NH, NZ), 256, 0, stream>>>(
        qb, kb, vT, msgacc, lacc);
    out_ln_mfma_kernel<<<NN / OROWS, 256, 0, stream>>>(msgacc, lacc, WoT, bo, x,
                                                       gamma, beta, out);
}

// Round 4
// 161.144 us; speedup vs baseline: 1.1671x; 1.1671x over previous
//
#include <hip/hip_runtime.h>
#include <hip/hip_bf16.h>
#include <math.h>

#define NN 4096      // nodes
#define C  256       // feature dim
#define NH 8         // heads
#define HD 32        // head dim
#define LN_EPS 1e-5f
#define LOG2E 1.44269504088896340736f

typedef unsigned short u16;
typedef __attribute__((ext_vector_type(8))) short bf16x8;
typedef __attribute__((ext_vector_type(4))) float f32x4;
typedef __attribute__((ext_vector_type(16))) float f32x16;

__device__ inline u16 f2b(float f) {
    union { float f; unsigned u; } v; v.f = f;
    unsigned r = (v.u + 0x7fff + ((v.u >> 16) & 1)) >> 16;  // RNE
    return (u16)r;
}

__device__ inline float fexp2(float x) {
#if __has_builtin(__builtin_amdgcn_exp2f)
    return __builtin_amdgcn_exp2f(x);      // single v_exp_f32
#else
    return exp2f(x);
#endif
}

// pack bf16(e0)|bf16(e1)<<16 by truncation: ONE v_perm_b32
__device__ inline unsigned pack_trunc(float e0, float e1) {
    return __builtin_amdgcn_perm(__float_as_uint(e1), __float_as_uint(e0),
                                 0x07060302u);
}

__device__ inline void atomic_add_agent(float* p, float v) {
    __hip_atomic_fetch_add(p, v, __ATOMIC_RELAXED, __HIP_MEMORY_SCOPE_AGENT);
}

__device__ inline f32x16 zero16() {
    return f32x16{0.f,0.f,0.f,0.f, 0.f,0.f,0.f,0.f,
                  0.f,0.f,0.f,0.f, 0.f,0.f,0.f,0.f};
}

// exp2 + bf16-pack + permlane32_swap: turns S^T chunk c (16 j per lane) into
// the PV A-fragment; accumulates row-sum of exps. Verified layout (round 1).
template<int c>
__device__ inline bf16x8 softmax_chunk(const f32x16 s, float& lsum) {
    const float e0 = fexp2(s[8*c+0]);
    const float e1 = fexp2(s[8*c+1]);
    const float e2 = fexp2(s[8*c+2]);
    const float e3 = fexp2(s[8*c+3]);
    const float e4 = fexp2(s[8*c+4]);
    const float e5 = fexp2(s[8*c+5]);
    const float e6 = fexp2(s[8*c+6]);
    const float e7 = fexp2(s[8*c+7]);
    lsum += ((e0 + e1) + (e2 + e3)) + ((e4 + e5) + (e6 + e7));
    const unsigned p01 = pack_trunc(e0, e1);
    const unsigned p23 = pack_trunc(e2, e3);
    const unsigned p45 = pack_trunc(e4, e5);
    const unsigned p67 = pack_trunc(e6, e7);
    const auto w02 = __builtin_amdgcn_permlane32_swap(p01, p45, false, false);
    const auto w13 = __builtin_amdgcn_permlane32_swap(p23, p67, false, false);
    union { unsigned w[4]; bf16x8 v; } pa;
    pa.w[0] = w02[0]; pa.w[1] = w13[0];
    pa.w[2] = w02[1]; pa.w[3] = w13[1];
    return pa.v;
}

// ---------------------------------------------------------------------------
// Kernel 0: prep — z<4: weight transpose+bf16 (WqkvT=[Wq^T|Wk^T|Wv^T], WoT);
// z>=4: x fp32->bf16 slice conversion (fused to save a dispatch).
// grid (8,8,8), block 256.
// ---------------------------------------------------------------------------
__global__ __launch_bounds__(256) void prep_kernel(
    const float* __restrict__ Wq, const float* __restrict__ Wk,
    const float* __restrict__ Wv, const float* __restrict__ Wo,
    const float* __restrict__ x,
    u16* __restrict__ WqkvT, u16* __restrict__ WoT, u16* __restrict__ xb)
{
    const int z = blockIdx.z;
    if (z < 4) {
        __shared__ float tile[32][33];
        const float* W = (z == 0) ? Wq : (z == 1) ? Wk : (z == 2) ? Wv : Wo;
        u16* WT = (z == 3) ? WoT : (WqkvT + (size_t)z * 256 * 256);
        const int tx = threadIdx.x & 31, ty = threadIdx.x >> 5;
        const int n0 = blockIdx.x * 32, k0 = blockIdx.y * 32;
        #pragma unroll
        for (int i = 0; i < 32; i += 8)
            tile[ty + i][tx] = W[(size_t)(k0 + ty + i) * 256 + n0 + tx];
        __syncthreads();
        #pragma unroll
        for (int i = 0; i < 32; i += 8)
            WT[(size_t)(n0 + ty + i) * 256 + k0 + tx] = f2b(tile[tx][ty + i]);
    } else {
        // x conversion: 4 slices x 64 blocks x 256 thr x 16 elems = NN*C
        const int slice = z - 4;
        const int bid = blockIdx.x * 8 + blockIdx.y;
        const int base = slice * (NN * C / 4) + bid * 4096 + threadIdx.x * 16;
        #pragma unroll
        for (int i = 0; i < 4; ++i) {
            const float4 v = *(const float4*)(x + base + i * 4);
            union { u16 u[4]; unsigned long long ull; } pk;
            pk.u[0] = f2b(v.x); pk.u[1] = f2b(v.y);
            pk.u[2] = f2b(v.z); pk.u[3] = f2b(v.w);
            *(unsigned long long*)(xb + base + i * 4) = pk.ull;
        }
    }
}

// ---------------------------------------------------------------------------
// Kernel 1: QKV projection via MFMA (64x64 tiles, 4 waves). A-frag is a
// single 16B load from pre-converted xb. qb pre-scaled by scale*log2e;
// v emitted as V^T.
// ---------------------------------------------------------------------------
__global__ __launch_bounds__(256) void qkv_mfma_kernel(
    const u16* __restrict__ xb, const u16* __restrict__ WT,
    const float* __restrict__ bq, const float* __restrict__ bk,
    const float* __restrict__ bv, const float* __restrict__ scale_p,
    u16* __restrict__ qb, u16* __restrict__ kb, u16* __restrict__ vT)
{
    const int m0 = blockIdx.x * 64;
    const int n0 = blockIdx.y * 64;
    const int t = threadIdx.x;
    const int wave = t >> 6, lane = t & 63;
    const int l16 = lane & 15, quad = lane >> 4;

    f32x4 acc[4];
    #pragma unroll
    for (int ct = 0; ct < 4; ++ct) acc[ct] = f32x4{0.f, 0.f, 0.f, 0.f};

    const u16* xrow = xb + (size_t)(m0 + wave * 16 + l16) * C;
    #pragma unroll
    for (int kk = 0; kk < 8; ++kk) {
        const bf16x8 af = *(const bf16x8*)(xrow + kk * 32 + quad * 8);
        #pragma unroll
        for (int ct = 0; ct < 4; ++ct) {
            const bf16x8 bfr = *(const bf16x8*)(
                WT + (size_t)(n0 + ct * 16 + l16) * C + kk * 32 + quad * 8);
            acc[ct] = __builtin_amdgcn_mfma_f32_16x16x32_bf16(af, bfr, acc[ct], 0, 0, 0);
        }
    }

    const int sect = n0 >> 8;
    const int c0 = n0 & 255;
    const int rbase = m0 + wave * 16 + quad * 4;
    if (sect == 0) {
        const float scl = (*scale_p) * LOG2E;
        #pragma unroll
        for (int ct = 0; ct < 4; ++ct) {
            const int c = c0 + ct * 16 + l16;
            const float b = bq[c];
            #pragma unroll
            for (int r = 0; r < 4; ++r)
                qb[(size_t)(rbase + r) * C + c] = f2b((acc[ct][r] + b) * scl);
        }
    } else if (sect == 1) {
        #pragma unroll
        for (int ct = 0; ct < 4; ++ct) {
            const int c = c0 + ct * 16 + l16;
            const float b = bk[c];
            #pragma unroll
            for (int r = 0; r < 4; ++r)
                kb[(size_t)(rbase + r) * C + c] = f2b(acc[ct][r] + b);
        }
    } else {
        #pragma unroll
        for (int ct = 0; ct < 4; ++ct) {
            const int c = c0 + ct * 16 + l16;
            const float b = bv[c];
            union { u16 u[4]; unsigned long long ull; } pk;
            #pragma unroll
            for (int r = 0; r < 4; ++r) pk.u[r] = f2b(acc[ct][r] + b);
            *(unsigned long long*)(vT + (size_t)c * NN + rbase) = pk.ull;
        }
    }
}

// ---------------------------------------------------------------------------
// Kernel 2: MFMA attention. 32x32x16, swapped QK^T, register-P via
// pack_trunc + permlane32_swap (verified round 1). K/V tiles staged in LDS
// in FRAGMENT ORDER ([frag][lane][16B] -> all LDS traffic is lane-linear
// b128, conflict-free by construction). Register-staged double buffer:
// ds_write(tile t) -> barrier -> issue global loads(tile t+1) -> compute.
// Each gather happens once per block (4 waves share); each wave owns 64
// q-rows. Unnormalized O and l accumulate via agent-scope fp32 atomics.
// ---------------------------------------------------------------------------
#define NZ 8
#define ZT (NN / NZ)       // 512 keys per z-slice
#define TQB 256            // q rows per block (64 per wave)
#define NIT (ZT / 64)      // 8 tiles of 64 keys

__global__ __launch_bounds__(256) void attn_mfma_kernel(
    const u16* __restrict__ q, const u16* __restrict__ k,
    const u16* __restrict__ vT, float* __restrict__ msgacc,
    float* __restrict__ lacc)
{
    // frag-order tiles: 4 frags x 64 lanes x 8 u16 = 2048 u16 = 4KB each
    __shared__ u16 Ks[2][2048];
    __shared__ u16 Vs[2][2048];

    const int h = blockIdx.y, z = blockIdx.z;
    const int t = threadIdx.x;
    const int w = t >> 6, lane = t & 63;
    const int l31 = lane & 31, hi = lane >> 5;
    const int qbase = blockIdx.x * TQB + w * 64;

    // Q B-frags for two 32-row groups: lane holds Q[q][d = hi*8+e (+16)]
    const u16* qrpA = q + (size_t)(qbase + l31) * C + h * HD + hi * 8;
    const bf16x8 qf0a = *(const bf16x8*)(qrpA);
    const bf16x8 qf1a = *(const bf16x8*)(qrpA + 16);
    const u16* qrpB = qrpA + 32 * C;
    const bf16x8 qf0b = *(const bf16x8*)(qrpB);
    const bf16x8 qf1b = *(const bf16x8*)(qrpB + 16);

    f32x16 oA = zero16(), oB = zero16();
    float lsA = 0.f, lsB = 0.f;

    // wave w stages fragment w: K[j-sub sst*32 + l31][col sfc*16 + hi*8],
    // vT[d = l31][j-sub sst*32 + sfc*16 + hi*8]
    const int sst = w >> 1, sfc = w & 1;
    const u16* gk = k + (size_t)(z * ZT + sst * 32 + l31) * C
                      + h * HD + sfc * 16 + hi * 8;
    const u16* gv = vT + (size_t)(h * HD + l31) * NN
                       + z * ZT + sst * 32 + sfc * 16 + hi * 8;

    // prologue: tile 0 into staging regs
    bf16x8 kreg = *(const bf16x8*)(gk);
    bf16x8 vreg = *(const bf16x8*)(gv);

    for (int it = 0; it < NIT; ++it) {
        const int b = it & 1;
        // commit staged tile to LDS (lane-linear, conflict-free)
        *(bf16x8*)(&Ks[b][w * 512 + lane * 8]) = kreg;
        *(bf16x8*)(&Vs[b][w * 512 + lane * 8]) = vreg;
        __syncthreads();

        // issue next tile's loads; consumed only at next iteration's
        // ds_write, so the whole compute phase hides the latency
        if (it + 1 < NIT) {
            kreg = *(const bf16x8*)(gk + (size_t)(it + 1) * 64 * C);
            vreg = *(const bf16x8*)(gv + (it + 1) * 64);
        }

        const u16* KsB = Ks[b];
        const u16* VsB = Vs[b];
        #pragma unroll
        for (int s = 0; s < 2; ++s) {
            const bf16x8 kf0 = *(const bf16x8*)(KsB + (s * 2 + 0) * 512 + lane * 8);
            const bf16x8 kf1 = *(const bf16x8*)(KsB + (s * 2 + 1) * 512 + lane * 8);
            const bf16x8 vf0 = *(const bf16x8*)(VsB + (s * 2 + 0) * 512 + lane * 8);
            const bf16x8 vf1 = *(const bf16x8*)(VsB + (s * 2 + 1) * 512 + lane * 8);

            // group A: QK^T (S^T = K Q^T), softmax, PV
            f32x16 sA = zero16();
            sA = __builtin_amdgcn_mfma_f32_32x32x16_bf16(kf0, qf0a, sA, 0, 0, 0);
            sA = __builtin_amdgcn_mfma_f32_32x32x16_bf16(kf1, qf1a, sA, 0, 0, 0);
            const bf16x8 paA0 = softmax_chunk<0>(sA, lsA);
            oA = __builtin_amdgcn_mfma_f32_32x32x16_bf16(paA0, vf0, oA, 0, 0, 0);
            const bf16x8 paA1 = softmax_chunk<1>(sA, lsA);
            oA = __builtin_amdgcn_mfma_f32_32x32x16_bf16(paA1, vf1, oA, 0, 0, 0);

            // group B
            f32x16 sB = zero16();
            sB = __builtin_amdgcn_mfma_f32_32x32x16_bf16(kf0, qf0b, sB, 0, 0, 0);
            sB = __builtin_amdgcn_mfma_f32_32x32x16_bf16(kf1, qf1b, sB, 0, 0, 0);
            const bf16x8 paB0 = softmax_chunk<0>(sB, lsB);
            oB = __builtin_amdgcn_mfma_f32_32x32x16_bf16(paB0, vf0, oB, 0, 0, 0);
            const bf16x8 paB1 = softmax_chunk<1>(sB, lsB);
            oB = __builtin_amdgcn_mfma_f32_32x32x16_bf16(paB1, vf1, oB, 0, 0, 0);
        }
        __syncthreads();   // reads drained before next iteration's ds_write
    }

    // lane's lsum covers 16 j per tile; xor-32 adds the partner half.
    lsA += __shfl_xor(lsA, 32);
    lsB += __shfl_xor(lsB, 32);
    if (hi == 0) {
        atomic_add_agent(&lacc[(size_t)(qbase + l31) * NH + h], lsA);
        atomic_add_agent(&lacc[(size_t)(qbase + 32 + l31) * NH + h], lsB);
    }

    #pragma unroll
    for (int r = 0; r < 16; ++r) {
        const int qrA = qbase + (r & 3) + 8 * (r >> 2) + 4 * hi;
        atomic_add_agent(&msgacc[(size_t)qrA * C + h * HD + l31], oA[r]);
        atomic_add_agent(&msgacc[(size_t)(qrA + 32) * C + h * HD + l31], oB[r]);
    }
}

// ---------------------------------------------------------------------------
// Kernel 3: y = x + (msgacc/l) @ Wo + bo, LayerNorm. 8-row tiles, 512 blocks.
// MFMA computes 16 rows; rows 8..15 discarded. Row-clamped loads.
// ---------------------------------------------------------------------------
#define OROWS 8
__global__ __launch_bounds__(256) void out_ln_mfma_kernel(
    const float* __restrict__ msgacc, const float* __restrict__ lacc,
    const u16* __restrict__ WoT, const float* __restrict__ bo,
    const float* __restrict__ x, const float* __restrict__ gamma,
    const float* __restrict__ beta, float* __restrict__ out)
{
    __shared__ float sums[2][4][OROWS];
    const int m0 = blockIdx.x * OROWS;
    const int t = threadIdx.x;
    const int w = t >> 6, lane = t & 63;
    const int l16 = lane & 15, quad = lane >> 4;

    f32x4 acc[4];
    #pragma unroll
    for (int ct = 0; ct < 4; ++ct) acc[ct] = f32x4{0.f, 0.f, 0.f, 0.f};

    const int ar = min(m0 + l16, NN - 1);
    const float* arow = msgacc + (size_t)ar * C;
    const float* lrow = lacc + (size_t)ar * NH;
    #pragma unroll
    for (int kk = 0; kk < 8; ++kk) {
        const float li = 1.f / lrow[kk];
        const float4 a0 = *(const float4*)(arow + kk * 32 + quad * 8);
        const float4 a1 = *(const float4*)(arow + kk * 32 + quad * 8 + 4);
        union { __hip_bfloat162 h2[4]; bf16x8 v; } af;
        af.h2[0] = __float22bfloat162_rn(float2{a0.x * li, a0.y * li});
        af.h2[1] = __float22bfloat162_rn(float2{a0.z * li, a0.w * li});
        af.h2[2] = __float22bfloat162_rn(float2{a1.x * li, a1.y * li});
        af.h2[3] = __float22bfloat162_rn(float2{a1.z * li, a1.w * li});
        #pragma unroll
        for (int ct = 0; ct < 4; ++ct) {
            const bf16x8 bfr = *(const bf16x8*)(
                WoT + (size_t)(w * 64 + ct * 16 + l16) * C + kk * 32 + quad * 8);
            acc[ct] = __builtin_amdgcn_mfma_f32_16x16x32_bf16(af.v, bfr, acc[ct], 0, 0, 0);
        }
    }

    float val[4][4];
    if (quad < 2) {
        #pragma unroll
        for (int r = 0; r < 4; ++r) {
            const int row = m0 + quad * 4 + r;
            float sr = 0.f, qr = 0.f;
            #pragma unroll
            for (int ct = 0; ct < 4; ++ct) {
                const int c = w * 64 + ct * 16 + l16;
                const float v = acc[ct][r] + bo[c] + x[(size_t)row * C + c];
                val[ct][r] = v;
                sr += v;
                qr = fmaf(v, v, qr);
            }
            sr += __shfl_xor(sr, 1); sr += __shfl_xor(sr, 2);
            sr += __shfl_xor(sr, 4); sr += __shfl_xor(sr, 8);
            qr += __shfl_xor(qr, 1); qr += __shfl_xor(qr, 2);
            qr += __shfl_xor(qr, 4); qr += __shfl_xor(qr, 8);
            if (l16 == 0) {
                sums[0][w][quad * 4 + r] = sr;
                sums[1][w][quad * 4 + r] = qr;
            }
        }
    }
    __syncthreads();

    if (quad < 2) {
        #pragma unroll
        for (int r = 0; r < 4; ++r) {
            const int ri = quad * 4 + r;
            const int row = m0 + ri;
            const float tot  = sums[0][0][ri] + sums[0][1][ri] + sums[0][2][ri] + sums[0][3][ri];
            const float tot2 = sums[1][0][ri] + sums[1][1][ri] + sums[1][2][ri] + sums[1][3][ri];
            const float mu = tot * (1.f / C);
            const float var = fmaxf(tot2 * (1.f / C) - mu * mu, 0.f);
            const float rstd = rsqrtf(var + LN_EPS);
            #pragma unroll
            for (int ct = 0; ct < 4; ++ct) {
                const int c = w * 64 + ct * 16 + l16;
                out[(size_t)row * C + c] = (val[ct][r] - mu) * rstd * gamma[c] + beta[c];
            }
        }
    }
}

// ---------------------------------------------------------------------------
extern "C" void kernel_launch(void* const* d_in, const int* in_sizes, int n_in,
                              void* d_out, int out_size, void* d_ws, size_t ws_size,
                              hipStream_t stream) {
    const float* x     = (const float*)d_in[0];
    const float* Wq    = (const float*)d_in[1];
    const float* bq    = (const float*)d_in[2];
    const float* Wk    = (const float*)d_in[3];
    const float* bk    = (const float*)d_in[4];
    const float* Wv    = (const float*)d_in[5];
    const float* bv    = (const float*)d_in[6];
    const float* scale = (const float*)d_in[7];
    const float* Wo    = (const float*)d_in[8];
    const float* bo    = (const float*)d_in[9];
    const float* gamma = (const float*)d_in[10];
    const float* beta  = (const float*)d_in[11];
    float* out = (float*)d_out;

    u16* qb     = (u16*)d_ws;                              // 2 MB
    u16* kb     = qb + (size_t)NN * C;                     // 2 MB
    u16* vT     = kb + (size_t)NN * C;                     // 2 MB
    u16* xbuf   = vT + (size_t)NN * C;                     // 2 MB
    u16* WqkvT  = xbuf + (size_t)NN * C;                   // 384 KB
    u16* WoT    = WqkvT + (size_t)3 * C * C;               // 128 KB
    float* msgacc = (float*)(WoT + (size_t)C * C);         // 4 MB
    float* lacc   = msgacc + (size_t)NN * C;               // 128 KB (contiguous)

    hipMemsetAsync(msgacc, 0, ((size_t)NN * C + (size_t)NN * NH) * sizeof(float),
                   stream);

    prep_kernel<<<dim3(8, 8, 8), 256, 0, stream>>>(Wq, Wk, Wv, Wo, x,
                                                   WqkvT, WoT, xbuf);
    qkv_mfma_kernel<<<dim3(NN / 64, 12), 256, 0, stream>>>(
        xbuf, WqkvT, bq, bk, bv, scale, qb, kb, vT);
    attn_mfma_kernel<<<dim3(NN / TQB, NH, NZ), 256, 0, stream>>>(
        qb, kb, vT, msgacc, lacc);
    out_ln_mfma_kernel<<<NN / OROWS, 256, 0, stream>>>(msgacc, lacc, WoT, bo, x,
                                                       gamma, beta, out);
}

// Round 5
// 153.955 us; speedup vs baseline: 1.2216x; 1.0467x over previous
//
#include <hip/hip_runtime.h>
#include <hip/hip_bf16.h>
#include <math.h>

#define NN 4096      // nodes
#define C  256       // feature dim
#define NH 8         // heads
#define HD 32        // head dim
#define LN_EPS 1e-5f
#define LOG2E 1.44269504088896340736f

#define NZ 4               // key-split factor (partial buffers, no atomics)
#define ZT (NN / NZ)       // 1024 keys per z-slice
#define TQB 128            // q rows per block (32 per wave)
#define NIT (ZT / 64)      // 16 tiles of 64 keys

typedef unsigned short u16;
typedef __attribute__((ext_vector_type(8))) short bf16x8;
typedef __attribute__((ext_vector_type(4))) float f32x4;
typedef __attribute__((ext_vector_type(16))) float f32x16;

__device__ inline u16 f2b(float f) {
    union { float f; unsigned u; } v; v.f = f;
    unsigned r = (v.u + 0x7fff + ((v.u >> 16) & 1)) >> 16;  // RNE
    return (u16)r;
}

__device__ inline float fexp2(float x) {
#if __has_builtin(__builtin_amdgcn_exp2f)
    return __builtin_amdgcn_exp2f(x);      // single v_exp_f32
#else
    return exp2f(x);
#endif
}

// pack bf16(e0)|bf16(e1)<<16 by truncation: ONE v_perm_b32
__device__ inline unsigned pack_trunc(float e0, float e1) {
    return __builtin_amdgcn_perm(__float_as_uint(e1), __float_as_uint(e0),
                                 0x07060302u);
}

__device__ inline f32x16 zero16() {
    return f32x16{0.f,0.f,0.f,0.f, 0.f,0.f,0.f,0.f,
                  0.f,0.f,0.f,0.f, 0.f,0.f,0.f,0.f};
}

// exp2 + bf16-pack + permlane32_swap: turns S^T chunk c (16 j per lane) into
// the PV A-fragment; accumulates row-sum of exps. Verified layout (round 1).
template<int c>
__device__ inline bf16x8 softmax_chunk(const f32x16 s, float& lsum) {
    const float e0 = fexp2(s[8*c+0]);
    const float e1 = fexp2(s[8*c+1]);
    const float e2 = fexp2(s[8*c+2]);
    const float e3 = fexp2(s[8*c+3]);
    const float e4 = fexp2(s[8*c+4]);
    const float e5 = fexp2(s[8*c+5]);
    const float e6 = fexp2(s[8*c+6]);
    const float e7 = fexp2(s[8*c+7]);
    lsum += ((e0 + e1) + (e2 + e3)) + ((e4 + e5) + (e6 + e7));
    const unsigned p01 = pack_trunc(e0, e1);
    const unsigned p23 = pack_trunc(e2, e3);
    const unsigned p45 = pack_trunc(e4, e5);
    const unsigned p67 = pack_trunc(e6, e7);
    const auto w02 = __builtin_amdgcn_permlane32_swap(p01, p45, false, false);
    const auto w13 = __builtin_amdgcn_permlane32_swap(p23, p67, false, false);
    union { unsigned w[4]; bf16x8 v; } pa;
    pa.w[0] = w02[0]; pa.w[1] = w13[0];
    pa.w[2] = w02[1]; pa.w[3] = w13[1];
    return pa.v;
}

// ---------------------------------------------------------------------------
// Kernel 0: prep — weight transpose + bf16 (WqkvT=[Wq^T|Wk^T|Wv^T], WoT).
// grid (8,8,4), block 256. (x conversion removed: qkv consumes f32 x.)
// ---------------------------------------------------------------------------
__global__ __launch_bounds__(256) void prep_kernel(
    const float* __restrict__ Wq, const float* __restrict__ Wk,
    const float* __restrict__ Wv, const float* __restrict__ Wo,
    u16* __restrict__ WqkvT, u16* __restrict__ WoT)
{
    __shared__ float tile[32][33];
    const int z = blockIdx.z;
    const float* W = (z == 0) ? Wq : (z == 1) ? Wk : (z == 2) ? Wv : Wo;
    u16* WT = (z == 3) ? WoT : (WqkvT + (size_t)z * 256 * 256);
    const int tx = threadIdx.x & 31, ty = threadIdx.x >> 5;
    const int n0 = blockIdx.x * 32, k0 = blockIdx.y * 32;
    #pragma unroll
    for (int i = 0; i < 32; i += 8)
        tile[ty + i][tx] = W[(size_t)(k0 + ty + i) * 256 + n0 + tx];
    __syncthreads();
    #pragma unroll
    for (int i = 0; i < 32; i += 8)
        WT[(size_t)(n0 + ty + i) * 256 + k0 + tx] = f2b(tile[tx][ty + i]);
}

// ---------------------------------------------------------------------------
// Kernel 1: QKV projection via MFMA (64x64 tiles, 4 waves). A-frag built
// directly from f32 x (2x float4 + RNE cvt). qb pre-scaled by scale*log2e;
// v emitted as V^T.
// ---------------------------------------------------------------------------
__global__ __launch_bounds__(256) void qkv_mfma_kernel(
    const float* __restrict__ x, const u16* __restrict__ WT,
    const float* __restrict__ bq, const float* __restrict__ bk,
    const float* __restrict__ bv, const float* __restrict__ scale_p,
    u16* __restrict__ qb, u16* __restrict__ kb, u16* __restrict__ vT)
{
    const int m0 = blockIdx.x * 64;
    const int n0 = blockIdx.y * 64;
    const int t = threadIdx.x;
    const int wave = t >> 6, lane = t & 63;
    const int l16 = lane & 15, quad = lane >> 4;

    f32x4 acc[4];
    #pragma unroll
    for (int ct = 0; ct < 4; ++ct) acc[ct] = f32x4{0.f, 0.f, 0.f, 0.f};

    const float* xrow = x + (size_t)(m0 + wave * 16 + l16) * C;
    #pragma unroll
    for (int kk = 0; kk < 8; ++kk) {
        const float4 a0 = *(const float4*)(xrow + kk * 32 + quad * 8);
        const float4 a1 = *(const float4*)(xrow + kk * 32 + quad * 8 + 4);
        union { __hip_bfloat162 h2[4]; bf16x8 v; } af;
        af.h2[0] = __float22bfloat162_rn(float2{a0.x, a0.y});
        af.h2[1] = __float22bfloat162_rn(float2{a0.z, a0.w});
        af.h2[2] = __float22bfloat162_rn(float2{a1.x, a1.y});
        af.h2[3] = __float22bfloat162_rn(float2{a1.z, a1.w});
        #pragma unroll
        for (int ct = 0; ct < 4; ++ct) {
            const bf16x8 bfr = *(const bf16x8*)(
                WT + (size_t)(n0 + ct * 16 + l16) * C + kk * 32 + quad * 8);
            acc[ct] = __builtin_amdgcn_mfma_f32_16x16x32_bf16(af.v, bfr, acc[ct], 0, 0, 0);
        }
    }

    const int sect = n0 >> 8;
    const int c0 = n0 & 255;
    const int rbase = m0 + wave * 16 + quad * 4;
    if (sect == 0) {
        const float scl = (*scale_p) * LOG2E;
        #pragma unroll
        for (int ct = 0; ct < 4; ++ct) {
            const int c = c0 + ct * 16 + l16;
            const float b = bq[c];
            #pragma unroll
            for (int r = 0; r < 4; ++r)
                qb[(size_t)(rbase + r) * C + c] = f2b((acc[ct][r] + b) * scl);
        }
    } else if (sect == 1) {
        #pragma unroll
        for (int ct = 0; ct < 4; ++ct) {
            const int c = c0 + ct * 16 + l16;
            const float b = bk[c];
            #pragma unroll
            for (int r = 0; r < 4; ++r)
                kb[(size_t)(rbase + r) * C + c] = f2b(acc[ct][r] + b);
        }
    } else {
        #pragma unroll
        for (int ct = 0; ct < 4; ++ct) {
            const int c = c0 + ct * 16 + l16;
            const float b = bv[c];
            union { u16 u[4]; unsigned long long ull; } pk;
            #pragma unroll
            for (int r = 0; r < 4; ++r) pk.u[r] = f2b(acc[ct][r] + b);
            *(unsigned long long*)(vT + (size_t)c * NN + rbase) = pk.ull;
        }
    }
}

// ---------------------------------------------------------------------------
// Kernel 2: MFMA attention. 32x32x16, swapped QK^T, register-P via
// pack_trunc + permlane32_swap. K/V tiles staged in frag-order LDS
// (lane-linear b128, conflict-free), register-staged double buffer.
// NO ATOMICS: each block writes its z-slice partial O (unnormalized) and
// partial l with plain coalesced stores; out_ln reduces over z.
// grid (32, 8, 4), 4 waves; each wave owns 32 q-rows.
// ---------------------------------------------------------------------------
__global__ __launch_bounds__(256) void attn_mfma_kernel(
    const u16* __restrict__ q, const u16* __restrict__ k,
    const u16* __restrict__ vT, float* __restrict__ msgp,
    float* __restrict__ lp)
{
    // frag-order tiles: 4 frags x 64 lanes x 8 u16 = 2048 u16 = 4KB each
    __shared__ u16 Ks[2][2048];
    __shared__ u16 Vs[2][2048];

    const int h = blockIdx.y, z = blockIdx.z;
    const int t = threadIdx.x;
    const int w = t >> 6, lane = t & 63;
    const int l31 = lane & 31, hi = lane >> 5;
    const int qbase = blockIdx.x * TQB + w * 32;

    // Q B-frag: lane holds Q[q = qbase+l31][d = hi*8+e (+16)]
    const u16* qrp = q + (size_t)(qbase + l31) * C + h * HD + hi * 8;
    const bf16x8 qf0 = *(const bf16x8*)(qrp);
    const bf16x8 qf1 = *(const bf16x8*)(qrp + 16);

    f32x16 o = zero16();
    float lsum = 0.f;

    // wave w stages fragment w: K[j-sub sst*32 + l31][col sfc*16 + hi*8],
    // vT[d = l31][j-sub sst*32 + sfc*16 + hi*8]
    const int sst = w >> 1, sfc = w & 1;
    const u16* gk = k + (size_t)(z * ZT + sst * 32 + l31) * C
                      + h * HD + sfc * 16 + hi * 8;
    const u16* gv = vT + (size_t)(h * HD + l31) * NN
                       + z * ZT + sst * 32 + sfc * 16 + hi * 8;

    // prologue: tile 0 into staging regs
    bf16x8 kreg = *(const bf16x8*)(gk);
    bf16x8 vreg = *(const bf16x8*)(gv);

    for (int it = 0; it < NIT; ++it) {
        const int b = it & 1;
        // commit staged tile to LDS (lane-linear, conflict-free)
        *(bf16x8*)(&Ks[b][w * 512 + lane * 8]) = kreg;
        *(bf16x8*)(&Vs[b][w * 512 + lane * 8]) = vreg;
        __syncthreads();

        // issue next tile's loads; consumed only at next iteration's
        // ds_write, so the whole compute phase hides the latency
        if (it + 1 < NIT) {
            kreg = *(const bf16x8*)(gk + (size_t)(it + 1) * 64 * C);
            vreg = *(const bf16x8*)(gv + (it + 1) * 64);
        }

        const u16* KsB = Ks[b];
        const u16* VsB = Vs[b];
        #pragma unroll
        for (int s = 0; s < 2; ++s) {
            const bf16x8 kf0 = *(const bf16x8*)(KsB + (s * 2 + 0) * 512 + lane * 8);
            const bf16x8 kf1 = *(const bf16x8*)(KsB + (s * 2 + 1) * 512 + lane * 8);
            const bf16x8 vf0 = *(const bf16x8*)(VsB + (s * 2 + 0) * 512 + lane * 8);
            const bf16x8 vf1 = *(const bf16x8*)(VsB + (s * 2 + 1) * 512 + lane * 8);

            // QK^T (S^T = K Q^T), softmax, PV
            f32x16 sA = zero16();
            sA = __builtin_amdgcn_mfma_f32_32x32x16_bf16(kf0, qf0, sA, 0, 0, 0);
            sA = __builtin_amdgcn_mfma_f32_32x32x16_bf16(kf1, qf1, sA, 0, 0, 0);
            const bf16x8 pa0 = softmax_chunk<0>(sA, lsum);
            o = __builtin_amdgcn_mfma_f32_32x32x16_bf16(pa0, vf0, o, 0, 0, 0);
            const bf16x8 pa1 = softmax_chunk<1>(sA, lsum);
            o = __builtin_amdgcn_mfma_f32_32x32x16_bf16(pa1, vf1, o, 0, 0, 0);
        }
        __syncthreads();   // reads drained before next iteration's ds_write
    }

    // lane's lsum covers 16 j per tile; xor-32 adds the partner half.
    lsum += __shfl_xor(lsum, 32);
    if (hi == 0)
        lp[((size_t)z * NH + h) * NN + qbase + l31] = lsum;

    #pragma unroll
    for (int r = 0; r < 16; ++r) {
        const int qr = qbase + (r & 3) + 8 * (r >> 2) + 4 * hi;
        msgp[((size_t)z * NN + qr) * C + h * HD + l31] = o[r];
    }
}

// ---------------------------------------------------------------------------
// Kernel 3: reduce z-partials, y = x + (msg/l) @ Wo + bo, LayerNorm.
// 8-row tiles, 512 blocks. MFMA computes 16 rows; rows 8..15 discarded.
// ---------------------------------------------------------------------------
#define OROWS 8
__global__ __launch_bounds__(256) void out_ln_mfma_kernel(
    const float* __restrict__ msgp, const float* __restrict__ lp,
    const u16* __restrict__ WoT, const float* __restrict__ bo,
    const float* __restrict__ x, const float* __restrict__ gamma,
    const float* __restrict__ beta, float* __restrict__ out)
{
    __shared__ float sums[2][4][OROWS];
    const int m0 = blockIdx.x * OROWS;
    const int t = threadIdx.x;
    const int w = t >> 6, lane = t & 63;
    const int l16 = lane & 15, quad = lane >> 4;

    f32x4 acc[4];
    #pragma unroll
    for (int ct = 0; ct < 4; ++ct) acc[ct] = f32x4{0.f, 0.f, 0.f, 0.f};

    const int ar = min(m0 + l16, NN - 1);
    #pragma unroll
    for (int kk = 0; kk < 8; ++kk) {
        float l = 0.f;
        #pragma unroll
        for (int z = 0; z < NZ; ++z)
            l += lp[((size_t)z * NH + kk) * NN + ar];
        const float li = 1.f / l;

        float4 a0 = float4{0.f, 0.f, 0.f, 0.f};
        float4 a1 = float4{0.f, 0.f, 0.f, 0.f};
        #pragma unroll
        for (int z = 0; z < NZ; ++z) {
            const float* arow = msgp + ((size_t)z * NN + ar) * C;
            const float4 b0 = *(const float4*)(arow + kk * 32 + quad * 8);
            const float4 b1 = *(const float4*)(arow + kk * 32 + quad * 8 + 4);
            a0.x += b0.x; a0.y += b0.y; a0.z += b0.z; a0.w += b0.w;
            a1.x += b1.x; a1.y += b1.y; a1.z += b1.z; a1.w += b1.w;
        }

        union { __hip_bfloat162 h2[4]; bf16x8 v; } af;
        af.h2[0] = __float22bfloat162_rn(float2{a0.x * li, a0.y * li});
        af.h2[1] = __float22bfloat162_rn(float2{a0.z * li, a0.w * li});
        af.h2[2] = __float22bfloat162_rn(float2{a1.x * li, a1.y * li});
        af.h2[3] = __float22bfloat162_rn(float2{a1.z * li, a1.w * li});
        #pragma unroll
        for (int ct = 0; ct < 4; ++ct) {
            const bf16x8 bfr = *(const bf16x8*)(
                WoT + (size_t)(w * 64 + ct * 16 + l16) * C + kk * 32 + quad * 8);
            acc[ct] = __builtin_amdgcn_mfma_f32_16x16x32_bf16(af.v, bfr, acc[ct], 0, 0, 0);
        }
    }

    float val[4][4];
    if (quad < 2) {
        #pragma unroll
        for (int r = 0; r < 4; ++r) {
            const int row = m0 + quad * 4 + r;
            float sr = 0.f, qr = 0.f;
            #pragma unroll
            for (int ct = 0; ct < 4; ++ct) {
                const int c = w * 64 + ct * 16 + l16;
                const float v = acc[ct][r] + bo[c] + x[(size_t)row * C + c];
                val[ct][r] = v;
                sr += v;
                qr = fmaf(v, v, qr);
            }
            sr += __shfl_xor(sr, 1); sr += __shfl_xor(sr, 2);
            sr += __shfl_xor(sr, 4); sr += __shfl_xor(sr, 8);
            qr += __shfl_xor(qr, 1); qr += __shfl_xor(qr, 2);
            qr += __shfl_xor(qr, 4); qr += __shfl_xor(qr, 8);
            if (l16 == 0) {
                sums[0][w][quad * 4 + r] = sr;
                sums[1][w][quad * 4 + r] = qr;
            }
        }
    }
    __syncthreads();

    if (quad < 2) {
        #pragma unroll
        for (int r = 0; r < 4; ++r) {
            const int ri = quad * 4 + r;
            const int row = m0 + ri;
            const float tot  = sums[0][0][ri] + sums[0][1][ri] + sums[0][2][ri] + sums[0][3][ri];
            const float tot2 = sums[1][0][ri] + sums[1][1][ri] + sums[1][2][ri] + sums[1][3][ri];
            const float mu = tot * (1.f / C);
            const float var = fmaxf(tot2 * (1.f / C) - mu * mu, 0.f);
            const float rstd = rsqrtf(var + LN_EPS);
            #pragma unroll
            for (int ct = 0; ct < 4; ++ct) {
                const int c = w * 64 + ct * 16 + l16;
                out[(size_t)row * C + c] = (val[ct][r] - mu) * rstd * gamma[c] + beta[c];
            }
        }
    }
}

// ---------------------------------------------------------------------------
extern "C" void kernel_launch(void* const* d_in, const int* in_sizes, int n_in,
                              void* d_out, int out_size, void* d_ws, size_t ws_size,
                              hipStream_t stream) {
    const float* x     = (const float*)d_in[0];
    const float* Wq    = (const float*)d_in[1];
    const float* bq    = (const float*)d_in[2];
    const float* Wk    = (const float*)d_in[3];
    const float* bk    = (const float*)d_in[4];
    const float* Wv    = (const float*)d_in[5];
    const float* bv    = (const float*)d_in[6];
    const float* scale = (const float*)d_in[7];
    const float* Wo    = (const float*)d_in[8];
    const float* bo    = (const float*)d_in[9];
    const float* gamma = (const float*)d_in[10];
    const float* beta  = (const float*)d_in[11];
    float* out = (float*)d_out;

    u16* qb     = (u16*)d_ws;                              // 2 MB
    u16* kb     = qb + (size_t)NN * C;                     // 2 MB
    u16* vT     = kb + (size_t)NN * C;                     // 2 MB
    u16* WqkvT  = vT + (size_t)NN * C;                     // 384 KB
    u16* WoT    = WqkvT + (size_t)3 * C * C;               // 128 KB
    float* msgp = (float*)(WoT + (size_t)C * C);           // NZ*4 MB = 16 MB
    float* lp   = msgp + (size_t)NZ * NN * C;              // 512 KB

    prep_kernel<<<dim3(8, 8, 4), 256, 0, stream>>>(Wq, Wk, Wv, Wo,
                                                   WqkvT, WoT);
    qkv_mfma_kernel<<<dim3(NN / 64, 12), 256, 0, stream>>>(
        x, WqkvT, bq, bk, bv, scale, qb, kb, vT);
    attn_mfma_kernel<<<dim3(NN / TQB, NH, NZ), 256, 0, stream>>>(
        qb, kb, vT, msgp, lp);
    out_ln_mfma_kernel<<<NN / OROWS, 256, 0, stream>>>(msgp, lp, WoT, bo, x,
                                                       gamma, beta, out);
}

// Round 6
// 152.751 us; speedup vs baseline: 1.2312x; 1.0079x over previous
//
#include <hip/hip_runtime.h>
#include <hip/hip_bf16.h>
#include <math.h>

#define NN 4096      // nodes
#define C  256       // feature dim
#define NH 8         // heads
#define HD 32        // head dim
#define LN_EPS 1e-5f
#define LOG2E 1.44269504088896340736f

#define NZ 8               // key-split factor (partial buffers, no atomics)
#define ZT (NN / NZ)       // 512 keys per z-slice
#define TQB 256            // q rows per block (64 per wave, 2 groups of 32)
#define NIT (ZT / 64)      // 8 tiles of 64 keys

typedef unsigned short u16;
typedef __attribute__((ext_vector_type(8))) short bf16x8;
typedef __attribute__((ext_vector_type(4))) float f32x4;
typedef __attribute__((ext_vector_type(16))) float f32x16;

__device__ inline u16 f2b(float f) {
    union { float f; unsigned u; } v; v.f = f;
    unsigned r = (v.u + 0x7fff + ((v.u >> 16) & 1)) >> 16;  // RNE
    return (u16)r;
}

__device__ inline float fexp2(float x) {
#if __has_builtin(__builtin_amdgcn_exp2f)
    return __builtin_amdgcn_exp2f(x);      // single v_exp_f32
#else
    return exp2f(x);
#endif
}

// pack bf16(e0)|bf16(e1)<<16 by truncation: ONE v_perm_b32
__device__ inline unsigned pack_trunc(float e0, float e1) {
    return __builtin_amdgcn_perm(__float_as_uint(e1), __float_as_uint(e0),
                                 0x07060302u);
}

__device__ inline f32x16 zero16() {
    return f32x16{0.f,0.f,0.f,0.f, 0.f,0.f,0.f,0.f,
                  0.f,0.f,0.f,0.f, 0.f,0.f,0.f,0.f};
}

// exp2 + bf16-pack + permlane32_swap: turns S^T chunk c (16 j per lane) into
// the PV A-fragment; accumulates row-sum of exps. Verified layout (round 1).
template<int c>
__device__ inline bf16x8 softmax_chunk(const f32x16 s, float& lsum) {
    const float e0 = fexp2(s[8*c+0]);
    const float e1 = fexp2(s[8*c+1]);
    const float e2 = fexp2(s[8*c+2]);
    const float e3 = fexp2(s[8*c+3]);
    const float e4 = fexp2(s[8*c+4]);
    const float e5 = fexp2(s[8*c+5]);
    const float e6 = fexp2(s[8*c+6]);
    const float e7 = fexp2(s[8*c+7]);
    lsum += ((e0 + e1) + (e2 + e3)) + ((e4 + e5) + (e6 + e7));
    const unsigned p01 = pack_trunc(e0, e1);
    const unsigned p23 = pack_trunc(e2, e3);
    const unsigned p45 = pack_trunc(e4, e5);
    const unsigned p67 = pack_trunc(e6, e7);
    const auto w02 = __builtin_amdgcn_permlane32_swap(p01, p45, false, false);
    const auto w13 = __builtin_amdgcn_permlane32_swap(p23, p67, false, false);
    union { unsigned w[4]; bf16x8 v; } pa;
    pa.w[0] = w02[0]; pa.w[1] = w13[0];
    pa.w[2] = w02[1]; pa.w[3] = w13[1];
    return pa.v;
}

// ---------------------------------------------------------------------------
// Kernel 0: prep — weight transpose + bf16 (WqkvT=[Wq^T|Wk^T|Wv^T], WoT).
// grid (8,8,4), block 256.
// ---------------------------------------------------------------------------
__global__ __launch_bounds__(256) void prep_kernel(
    const float* __restrict__ Wq, const float* __restrict__ Wk,
    const float* __restrict__ Wv, const float* __restrict__ Wo,
    u16* __restrict__ WqkvT, u16* __restrict__ WoT)
{
    __shared__ float tile[32][33];
    const int z = blockIdx.z;
    const float* W = (z == 0) ? Wq : (z == 1) ? Wk : (z == 2) ? Wv : Wo;
    u16* WT = (z == 3) ? WoT : (WqkvT + (size_t)z * 256 * 256);
    const int tx = threadIdx.x & 31, ty = threadIdx.x >> 5;
    const int n0 = blockIdx.x * 32, k0 = blockIdx.y * 32;
    #pragma unroll
    for (int i = 0; i < 32; i += 8)
        tile[ty + i][tx] = W[(size_t)(k0 + ty + i) * 256 + n0 + tx];
    __syncthreads();
    #pragma unroll
    for (int i = 0; i < 32; i += 8)
        WT[(size_t)(n0 + ty + i) * 256 + k0 + tx] = f2b(tile[tx][ty + i]);
}

// ---------------------------------------------------------------------------
// Kernel 1: QKV projection via MFMA (64x64 tiles, 4 waves). A-frag built
// directly from f32 x (2x float4 + RNE cvt). qb pre-scaled by scale*log2e;
// v emitted as V^T.
// ---------------------------------------------------------------------------
__global__ __launch_bounds__(256) void qkv_mfma_kernel(
    const float* __restrict__ x, const u16* __restrict__ WT,
    const float* __restrict__ bq, const float* __restrict__ bk,
    const float* __restrict__ bv, const float* __restrict__ scale_p,
    u16* __restrict__ qb, u16* __restrict__ kb, u16* __restrict__ vT)
{
    const int m0 = blockIdx.x * 64;
    const int n0 = blockIdx.y * 64;
    const int t = threadIdx.x;
    const int wave = t >> 6, lane = t & 63;
    const int l16 = lane & 15, quad = lane >> 4;

    f32x4 acc[4];
    #pragma unroll
    for (int ct = 0; ct < 4; ++ct) acc[ct] = f32x4{0.f, 0.f, 0.f, 0.f};

    const float* xrow = x + (size_t)(m0 + wave * 16 + l16) * C;
    #pragma unroll
    for (int kk = 0; kk < 8; ++kk) {
        const float4 a0 = *(const float4*)(xrow + kk * 32 + quad * 8);
        const float4 a1 = *(const float4*)(xrow + kk * 32 + quad * 8 + 4);
        union { __hip_bfloat162 h2[4]; bf16x8 v; } af;
        af.h2[0] = __float22bfloat162_rn(float2{a0.x, a0.y});
        af.h2[1] = __float22bfloat162_rn(float2{a0.z, a0.w});
        af.h2[2] = __float22bfloat162_rn(float2{a1.x, a1.y});
        af.h2[3] = __float22bfloat162_rn(float2{a1.z, a1.w});
        #pragma unroll
        for (int ct = 0; ct < 4; ++ct) {
            const bf16x8 bfr = *(const bf16x8*)(
                WT + (size_t)(n0 + ct * 16 + l16) * C + kk * 32 + quad * 8);
            acc[ct] = __builtin_amdgcn_mfma_f32_16x16x32_bf16(af.v, bfr, acc[ct], 0, 0, 0);
        }
    }

    const int sect = n0 >> 8;
    const int c0 = n0 & 255;
    const int rbase = m0 + wave * 16 + quad * 4;
    if (sect == 0) {
        const float scl = (*scale_p) * LOG2E;
        #pragma unroll
        for (int ct = 0; ct < 4; ++ct) {
            const int c = c0 + ct * 16 + l16;
            const float b = bq[c];
            #pragma unroll
            for (int r = 0; r < 4; ++r)
                qb[(size_t)(rbase + r) * C + c] = f2b((acc[ct][r] + b) * scl);
        }
    } else if (sect == 1) {
        #pragma unroll
        for (int ct = 0; ct < 4; ++ct) {
            const int c = c0 + ct * 16 + l16;
            const float b = bk[c];
            #pragma unroll
            for (int r = 0; r < 4; ++r)
                kb[(size_t)(rbase + r) * C + c] = f2b(acc[ct][r] + b);
        }
    } else {
        #pragma unroll
        for (int ct = 0; ct < 4; ++ct) {
            const int c = c0 + ct * 16 + l16;
            const float b = bv[c];
            union { u16 u[4]; unsigned long long ull; } pk;
            #pragma unroll
            for (int r = 0; r < 4; ++r) pk.u[r] = f2b(acc[ct][r] + b);
            *(unsigned long long*)(vT + (size_t)c * NN + rbase) = pk.ull;
        }
    }
}

// ---------------------------------------------------------------------------
// Kernel 2: MFMA attention. 32x32x16, swapped QK^T, register-P via
// pack_trunc + permlane32_swap. K/V tiles staged in frag-order LDS
// (lane-linear b128, conflict-free), register-staged double buffer.
// Dual Q-groups per wave (64 q-rows): every K/V fragment feeds 2 Q-frags,
// halving staging + LDS-read per unit work (round-4-verified inner loop).
// NO ATOMICS: plain coalesced stores of z-slice partial O and l.
// grid (16, 8, 8), 4 waves.
// ---------------------------------------------------------------------------
__global__ __launch_bounds__(256) void attn_mfma_kernel(
    const u16* __restrict__ q, const u16* __restrict__ k,
    const u16* __restrict__ vT, float* __restrict__ msgp,
    float* __restrict__ lp)
{
    // frag-order tiles: 4 frags x 64 lanes x 8 u16 = 2048 u16 = 4KB each
    __shared__ u16 Ks[2][2048];
    __shared__ u16 Vs[2][2048];

    const int h = blockIdx.y, z = blockIdx.z;
    const int t = threadIdx.x;
    const int w = t >> 6, lane = t & 63;
    const int l31 = lane & 31, hi = lane >> 5;
    const int qbase = blockIdx.x * TQB + w * 64;

    // Q B-frags for two 32-row groups: lane holds Q[q][d = hi*8+e (+16)]
    const u16* qrpA = q + (size_t)(qbase + l31) * C + h * HD + hi * 8;
    const bf16x8 qf0a = *(const bf16x8*)(qrpA);
    const bf16x8 qf1a = *(const bf16x8*)(qrpA + 16);
    const u16* qrpB = qrpA + 32 * C;
    const bf16x8 qf0b = *(const bf16x8*)(qrpB);
    const bf16x8 qf1b = *(const bf16x8*)(qrpB + 16);

    f32x16 oA = zero16(), oB = zero16();
    float lsA = 0.f, lsB = 0.f;

    // wave w stages fragment w: K[j-sub sst*32 + l31][col sfc*16 + hi*8],
    // vT[d = l31][j-sub sst*32 + sfc*16 + hi*8]
    const int sst = w >> 1, sfc = w & 1;
    const u16* gk = k + (size_t)(z * ZT + sst * 32 + l31) * C
                      + h * HD + sfc * 16 + hi * 8;
    const u16* gv = vT + (size_t)(h * HD + l31) * NN
                       + z * ZT + sst * 32 + sfc * 16 + hi * 8;

    // prologue: tile 0 into staging regs
    bf16x8 kreg = *(const bf16x8*)(gk);
    bf16x8 vreg = *(const bf16x8*)(gv);

    for (int it = 0; it < NIT; ++it) {
        const int b = it & 1;
        // commit staged tile to LDS (lane-linear, conflict-free)
        *(bf16x8*)(&Ks[b][w * 512 + lane * 8]) = kreg;
        *(bf16x8*)(&Vs[b][w * 512 + lane * 8]) = vreg;
        __syncthreads();

        // issue next tile's loads; consumed only at next iteration's
        // ds_write, so the whole compute phase hides the latency
        if (it + 1 < NIT) {
            kreg = *(const bf16x8*)(gk + (size_t)(it + 1) * 64 * C);
            vreg = *(const bf16x8*)(gv + (it + 1) * 64);
        }

        const u16* KsB = Ks[b];
        const u16* VsB = Vs[b];
        #pragma unroll
        for (int s = 0; s < 2; ++s) {
            const bf16x8 kf0 = *(const bf16x8*)(KsB + (s * 2 + 0) * 512 + lane * 8);
            const bf16x8 kf1 = *(const bf16x8*)(KsB + (s * 2 + 1) * 512 + lane * 8);
            const bf16x8 vf0 = *(const bf16x8*)(VsB + (s * 2 + 0) * 512 + lane * 8);
            const bf16x8 vf1 = *(const bf16x8*)(VsB + (s * 2 + 1) * 512 + lane * 8);

            // group A: QK^T (S^T = K Q^T), softmax, PV
            f32x16 sA = zero16();
            sA = __builtin_amdgcn_mfma_f32_32x32x16_bf16(kf0, qf0a, sA, 0, 0, 0);
            sA = __builtin_amdgcn_mfma_f32_32x32x16_bf16(kf1, qf1a, sA, 0, 0, 0);
            const bf16x8 paA0 = softmax_chunk<0>(sA, lsA);
            oA = __builtin_amdgcn_mfma_f32_32x32x16_bf16(paA0, vf0, oA, 0, 0, 0);
            const bf16x8 paA1 = softmax_chunk<1>(sA, lsA);
            oA = __builtin_amdgcn_mfma_f32_32x32x16_bf16(paA1, vf1, oA, 0, 0, 0);

            // group B
            f32x16 sB = zero16();
            sB = __builtin_amdgcn_mfma_f32_32x32x16_bf16(kf0, qf0b, sB, 0, 0, 0);
            sB = __builtin_amdgcn_mfma_f32_32x32x16_bf16(kf1, qf1b, sB, 0, 0, 0);
            const bf16x8 paB0 = softmax_chunk<0>(sB, lsB);
            oB = __builtin_amdgcn_mfma_f32_32x32x16_bf16(paB0, vf0, oB, 0, 0, 0);
            const bf16x8 paB1 = softmax_chunk<1>(sB, lsB);
            oB = __builtin_amdgcn_mfma_f32_32x32x16_bf16(paB1, vf1, oB, 0, 0, 0);
        }
        __syncthreads();   // reads drained before next iteration's ds_write
    }

    // lane's lsum covers 16 j per tile; xor-32 adds the partner half.
    lsA += __shfl_xor(lsA, 32);
    lsB += __shfl_xor(lsB, 32);
    if (hi == 0) {
        lp[((size_t)z * NH + h) * NN + qbase + l31] = lsA;
        lp[((size_t)z * NH + h) * NN + qbase + 32 + l31] = lsB;
    }

    #pragma unroll
    for (int r = 0; r < 16; ++r) {
        const int qrA = qbase + (r & 3) + 8 * (r >> 2) + 4 * hi;
        msgp[((size_t)z * NN + qrA) * C + h * HD + l31] = oA[r];
        msgp[((size_t)z * NN + qrA + 32) * C + h * HD + l31] = oB[r];
    }
}

// ---------------------------------------------------------------------------
// Kernel 3: reduce z-partials, y = x + (msg/l) @ Wo + bo, LayerNorm.
// 16-row tiles (ALL MFMA rows used), 256 blocks.
// ---------------------------------------------------------------------------
#define OROWS 16
__global__ __launch_bounds__(256) void out_ln_mfma_kernel(
    const float* __restrict__ msgp, const float* __restrict__ lp,
    const u16* __restrict__ WoT, const float* __restrict__ bo,
    const float* __restrict__ x, const float* __restrict__ gamma,
    const float* __restrict__ beta, float* __restrict__ out)
{
    __shared__ float sums[2][4][OROWS];
    const int m0 = blockIdx.x * OROWS;
    const int t = threadIdx.x;
    const int w = t >> 6, lane = t & 63;
    const int l16 = lane & 15, quad = lane >> 4;

    f32x4 acc[4];
    #pragma unroll
    for (int ct = 0; ct < 4; ++ct) acc[ct] = f32x4{0.f, 0.f, 0.f, 0.f};

    const int ar = m0 + l16;   // exact: 256 blocks x 16 rows = NN
    #pragma unroll
    for (int kk = 0; kk < 8; ++kk) {
        float l = 0.f;
        #pragma unroll
        for (int z = 0; z < NZ; ++z)
            l += lp[((size_t)z * NH + kk) * NN + ar];
        const float li = 1.f / l;

        float4 a0 = float4{0.f, 0.f, 0.f, 0.f};
        float4 a1 = float4{0.f, 0.f, 0.f, 0.f};
        #pragma unroll
        for (int z = 0; z < NZ; ++z) {
            const float* arow = msgp + ((size_t)z * NN + ar) * C;
            const float4 b0 = *(const float4*)(arow + kk * 32 + quad * 8);
            const float4 b1 = *(const float4*)(arow + kk * 32 + quad * 8 + 4);
            a0.x += b0.x; a0.y += b0.y; a0.z += b0.z; a0.w += b0.w;
            a1.x += b1.x; a1.y += b1.y; a1.z += b1.z; a1.w += b1.w;
        }

        union { __hip_bfloat162 h2[4]; bf16x8 v; } af;
        af.h2[0] = __float22bfloat162_rn(float2{a0.x * li, a0.y * li});
        af.h2[1] = __float22bfloat162_rn(float2{a0.z * li, a0.w * li});
        af.h2[2] = __float22bfloat162_rn(float2{a1.x * li, a1.y * li});
        af.h2[3] = __float22bfloat162_rn(float2{a1.z * li, a1.w * li});
        #pragma unroll
        for (int ct = 0; ct < 4; ++ct) {
            const bf16x8 bfr = *(const bf16x8*)(
                WoT + (size_t)(w * 64 + ct * 16 + l16) * C + kk * 32 + quad * 8);
            acc[ct] = __builtin_amdgcn_mfma_f32_16x16x32_bf16(af.v, bfr, acc[ct], 0, 0, 0);
        }
    }

    float val[4][4];
    #pragma unroll
    for (int r = 0; r < 4; ++r) {
        const int row = m0 + quad * 4 + r;
        float sr = 0.f, qr = 0.f;
        #pragma unroll
        for (int ct = 0; ct < 4; ++ct) {
            const int c = w * 64 + ct * 16 + l16;
            const float v = acc[ct][r] + bo[c] + x[(size_t)row * C + c];
            val[ct][r] = v;
            sr += v;
            qr = fmaf(v, v, qr);
        }
        sr += __shfl_xor(sr, 1); sr += __shfl_xor(sr, 2);
        sr += __shfl_xor(sr, 4); sr += __shfl_xor(sr, 8);
        qr += __shfl_xor(qr, 1); qr += __shfl_xor(qr, 2);
        qr += __shfl_xor(qr, 4); qr += __shfl_xor(qr, 8);
        if (l16 == 0) {
            sums[0][w][quad * 4 + r] = sr;
            sums[1][w][quad * 4 + r] = qr;
        }
    }
    __syncthreads();

    #pragma unroll
    for (int r = 0; r < 4; ++r) {
        const int ri = quad * 4 + r;
        const int row = m0 + ri;
        const float tot  = sums[0][0][ri] + sums[0][1][ri] + sums[0][2][ri] + sums[0][3][ri];
        const float tot2 = sums[1][0][ri] + sums[1][1][ri] + sums[1][2][ri] + sums[1][3][ri];
        const float mu = tot * (1.f / C);
        const float var = fmaxf(tot2 * (1.f / C) - mu * mu, 0.f);
        const float rstd = rsqrtf(var + LN_EPS);
        #pragma unroll
        for (int ct = 0; ct < 4; ++ct) {
            const int c = w * 64 + ct * 16 + l16;
            out[(size_t)row * C + c] = (val[ct][r] - mu) * rstd * gamma[c] + beta[c];
        }
    }
}

// ---------------------------------------------------------------------------
extern "C" void kernel_launch(void* const* d_in, const int* in_sizes, int n_in,
                              void* d_out, int out_size, void* d_ws, size_t ws_size,
                              hipStream_t stream) {
    const float* x     = (const float*)d_in[0];
    const float* Wq    = (const float*)d_in[1];
    const float* bq    = (const float*)d_in[2];
    const float* Wk    = (const float*)d_in[3];
    const float* bk    = (const float*)d_in[4];
    const float* Wv    = (const float*)d_in[5];
    const float* bv    = (const float*)d_in[6];
    const float* scale = (const float*)d_in[7];
    const float* Wo    = (const float*)d_in[8];
    const float* bo    = (const float*)d_in[9];
    const float* gamma = (const float*)d_in[10];
    const float* beta  = (const float*)d_in[11];
    float* out = (float*)d_out;

    u16* qb     = (u16*)d_ws;                              // 2 MB
    u16* kb     = qb + (size_t)NN * C;                     // 2 MB
    u16* vT     = kb + (size_t)NN * C;                     // 2 MB
    u16* WqkvT  = vT + (size_t)NN * C;                     // 384 KB
    u16* WoT    = WqkvT + (size_t)3 * C * C;               // 128 KB
    float* msgp = (float*)(WoT + (size_t)C * C);           // NZ*4 MB = 32 MB
    float* lp   = msgp + (size_t)NZ * NN * C;              // 1 MB

    prep_kernel<<<dim3(8, 8, 4), 256, 0, stream>>>(Wq, Wk, Wv, Wo,
                                                   WqkvT, WoT);
    qkv_mfma_kernel<<<dim3(NN / 64, 12), 256, 0, stream>>>(
        x, WqkvT, bq, bk, bv, scale, qb, kb, vT);
    attn_mfma_kernel<<<dim3(NN / TQB, NH, NZ), 256, 0, stream>>>(
        qb, kb, vT, msgp, lp);
    out_ln_mfma_kernel<<<NN / OROWS, 256, 0, stream>>>(msgp, lp, WoT, bo, x,
                                                       gamma, beta, out);
}

// Round 7
// 145.163 us; speedup vs baseline: 1.2956x; 1.0523x over previous
//
#include <hip/hip_runtime.h>
#include <hip/hip_bf16.h>
#include <math.h>

#define NN 4096      // nodes
#define C  256       // feature dim
#define NH 8         // heads
#define HD 32        // head dim
#define LN_EPS 1e-5f
#define LOG2E 1.44269504088896340736f

#define NZ 4               // key-split factor (partial buffers, no atomics)
#define ZT (NN / NZ)       // 1024 keys per z-slice
#define TQB 256            // q rows per block (64 per wave, 2 groups of 32)
#define NIT (ZT / 64)      // 16 tiles of 64 keys

typedef unsigned short u16;
typedef __attribute__((ext_vector_type(8))) short bf16x8;
typedef __attribute__((ext_vector_type(4))) float f32x4;
typedef __attribute__((ext_vector_type(16))) float f32x16;

__device__ inline u16 f2b(float f) {
    union { float f; unsigned u; } v; v.f = f;
    unsigned r = (v.u + 0x7fff + ((v.u >> 16) & 1)) >> 16;  // RNE
    return (u16)r;
}

__device__ inline float fexp2(float x) {
#if __has_builtin(__builtin_amdgcn_exp2f)
    return __builtin_amdgcn_exp2f(x);      // single v_exp_f32
#else
    return exp2f(x);
#endif
}

// pack bf16(e0)|bf16(e1)<<16 by truncation: ONE v_perm_b32
__device__ inline unsigned pack_trunc(float e0, float e1) {
    return __builtin_amdgcn_perm(__float_as_uint(e1), __float_as_uint(e0),
                                 0x07060302u);
}

__device__ inline f32x16 zero16() {
    return f32x16{0.f,0.f,0.f,0.f, 0.f,0.f,0.f,0.f,
                  0.f,0.f,0.f,0.f, 0.f,0.f,0.f,0.f};
}

// exp2 + bf16-pack + permlane32_swap: turns S^T chunk c (16 j per lane) into
// the PV A-fragment; accumulates row-sum of exps. Verified layout (round 1).
template<int c>
__device__ inline bf16x8 softmax_chunk(const f32x16 s, float& lsum) {
    const float e0 = fexp2(s[8*c+0]);
    const float e1 = fexp2(s[8*c+1]);
    const float e2 = fexp2(s[8*c+2]);
    const float e3 = fexp2(s[8*c+3]);
    const float e4 = fexp2(s[8*c+4]);
    const float e5 = fexp2(s[8*c+5]);
    const float e6 = fexp2(s[8*c+6]);
    const float e7 = fexp2(s[8*c+7]);
    lsum += ((e0 + e1) + (e2 + e3)) + ((e4 + e5) + (e6 + e7));
    const unsigned p01 = pack_trunc(e0, e1);
    const unsigned p23 = pack_trunc(e2, e3);
    const unsigned p45 = pack_trunc(e4, e5);
    const unsigned p67 = pack_trunc(e6, e7);
    const auto w02 = __builtin_amdgcn_permlane32_swap(p01, p45, false, false);
    const auto w13 = __builtin_amdgcn_permlane32_swap(p23, p67, false, false);
    union { unsigned w[4]; bf16x8 v; } pa;
    pa.w[0] = w02[0]; pa.w[1] = w13[0];
    pa.w[2] = w02[1]; pa.w[3] = w13[1];
    return pa.v;
}

// ---------------------------------------------------------------------------
// Kernel 0: prep — weight transpose + bf16 (WqkvT=[Wq^T|Wk^T|Wv^T], WoT).
// grid (8,8,4), block 256.
// ---------------------------------------------------------------------------
__global__ __launch_bounds__(256) void prep_kernel(
    const float* __restrict__ Wq, const float* __restrict__ Wk,
    const float* __restrict__ Wv, const float* __restrict__ Wo,
    u16* __restrict__ WqkvT, u16* __restrict__ WoT)
{
    __shared__ float tile[32][33];
    const int z = blockIdx.z;
    const float* W = (z == 0) ? Wq : (z == 1) ? Wk : (z == 2) ? Wv : Wo;
    u16* WT = (z == 3) ? WoT : (WqkvT + (size_t)z * 256 * 256);
    const int tx = threadIdx.x & 31, ty = threadIdx.x >> 5;
    const int n0 = blockIdx.x * 32, k0 = blockIdx.y * 32;
    #pragma unroll
    for (int i = 0; i < 32; i += 8)
        tile[ty + i][tx] = W[(size_t)(k0 + ty + i) * 256 + n0 + tx];
    __syncthreads();
    #pragma unroll
    for (int i = 0; i < 32; i += 8)
        WT[(size_t)(n0 + ty + i) * 256 + k0 + tx] = f2b(tile[tx][ty + i]);
}

// ---------------------------------------------------------------------------
// Kernel 1: QKV projection via MFMA (64x64 tiles, 4 waves). A-frag built
// directly from f32 x (2x float4 + RNE cvt). qb pre-scaled by scale*log2e;
// v emitted as V^T.
// ---------------------------------------------------------------------------
__global__ __launch_bounds__(256) void qkv_mfma_kernel(
    const float* __restrict__ x, const u16* __restrict__ WT,
    const float* __restrict__ bq, const float* __restrict__ bk,
    const float* __restrict__ bv, const float* __restrict__ scale_p,
    u16* __restrict__ qb, u16* __restrict__ kb, u16* __restrict__ vT)
{
    const int m0 = blockIdx.x * 64;
    const int n0 = blockIdx.y * 64;
    const int t = threadIdx.x;
    const int wave = t >> 6, lane = t & 63;
    const int l16 = lane & 15, quad = lane >> 4;

    f32x4 acc[4];
    #pragma unroll
    for (int ct = 0; ct < 4; ++ct) acc[ct] = f32x4{0.f, 0.f, 0.f, 0.f};

    const float* xrow = x + (size_t)(m0 + wave * 16 + l16) * C;
    #pragma unroll
    for (int kk = 0; kk < 8; ++kk) {
        const float4 a0 = *(const float4*)(xrow + kk * 32 + quad * 8);
        const float4 a1 = *(const float4*)(xrow + kk * 32 + quad * 8 + 4);
        union { __hip_bfloat162 h2[4]; bf16x8 v; } af;
        af.h2[0] = __float22bfloat162_rn(float2{a0.x, a0.y});
        af.h2[1] = __float22bfloat162_rn(float2{a0.z, a0.w});
        af.h2[2] = __float22bfloat162_rn(float2{a1.x, a1.y});
        af.h2[3] = __float22bfloat162_rn(float2{a1.z, a1.w});
        #pragma unroll
        for (int ct = 0; ct < 4; ++ct) {
            const bf16x8 bfr = *(const bf16x8*)(
                WT + (size_t)(n0 + ct * 16 + l16) * C + kk * 32 + quad * 8);
            acc[ct] = __builtin_amdgcn_mfma_f32_16x16x32_bf16(af.v, bfr, acc[ct], 0, 0, 0);
        }
    }

    const int sect = n0 >> 8;
    const int c0 = n0 & 255;
    const int rbase = m0 + wave * 16 + quad * 4;
    if (sect == 0) {
        const float scl = (*scale_p) * LOG2E;
        #pragma unroll
        for (int ct = 0; ct < 4; ++ct) {
            const int c = c0 + ct * 16 + l16;
            const float b = bq[c];
            #pragma unroll
            for (int r = 0; r < 4; ++r)
                qb[(size_t)(rbase + r) * C + c] = f2b((acc[ct][r] + b) * scl);
        }
    } else if (sect == 1) {
        #pragma unroll
        for (int ct = 0; ct < 4; ++ct) {
            const int c = c0 + ct * 16 + l16;
            const float b = bk[c];
            #pragma unroll
            for (int r = 0; r < 4; ++r)
                kb[(size_t)(rbase + r) * C + c] = f2b(acc[ct][r] + b);
        }
    } else {
        #pragma unroll
        for (int ct = 0; ct < 4; ++ct) {
            const int c = c0 + ct * 16 + l16;
            const float b = bv[c];
            union { u16 u[4]; unsigned long long ull; } pk;
            #pragma unroll
            for (int r = 0; r < 4; ++r) pk.u[r] = f2b(acc[ct][r] + b);
            *(unsigned long long*)(vT + (size_t)c * NN + rbase) = pk.ull;
        }
    }
}

// ---------------------------------------------------------------------------
// Kernel 2: MFMA attention. 32x32x16, swapped QK^T, register-P via
// pack_trunc + permlane32_swap. K/V tiles staged in frag-order LDS
// (lane-linear b128, conflict-free), register-staged double buffer with a
// SINGLE barrier per tile (writes of tile t+1 target the opposite LDS
// buffer from tile t's reads, so no trailing barrier is needed).
// Dual Q-groups per wave (64 q-rows): every K/V fragment feeds 2 Q-frags.
// NO ATOMICS: plain coalesced stores of z-slice partial O and l.
// grid (16, 8, 4), 4 waves.
// ---------------------------------------------------------------------------
__global__ __launch_bounds__(256) void attn_mfma_kernel(
    const u16* __restrict__ q, const u16* __restrict__ k,
    const u16* __restrict__ vT, float* __restrict__ msgp,
    float* __restrict__ lp)
{
    // frag-order tiles: 4 frags x 64 lanes x 8 u16 = 2048 u16 = 4KB each
    __shared__ u16 Ks[2][2048];
    __shared__ u16 Vs[2][2048];

    const int h = blockIdx.y, z = blockIdx.z;
    const int t = threadIdx.x;
    const int w = t >> 6, lane = t & 63;
    const int l31 = lane & 31, hi = lane >> 5;
    const int qbase = blockIdx.x * TQB + w * 64;

    // Q B-frags for two 32-row groups: lane holds Q[q][d = hi*8+e (+16)]
    const u16* qrpA = q + (size_t)(qbase + l31) * C + h * HD + hi * 8;
    const bf16x8 qf0a = *(const bf16x8*)(qrpA);
    const bf16x8 qf1a = *(const bf16x8*)(qrpA + 16);
    const u16* qrpB = qrpA + 32 * C;
    const bf16x8 qf0b = *(const bf16x8*)(qrpB);
    const bf16x8 qf1b = *(const bf16x8*)(qrpB + 16);

    f32x16 oA = zero16(), oB = zero16();
    float lsA = 0.f, lsB = 0.f;

    // wave w stages fragment w: K[j-sub sst*32 + l31][col sfc*16 + hi*8],
    // vT[d = l31][j-sub sst*32 + sfc*16 + hi*8]
    const int sst = w >> 1, sfc = w & 1;
    const u16* gk = k + (size_t)(z * ZT + sst * 32 + l31) * C
                      + h * HD + sfc * 16 + hi * 8;
    const u16* gv = vT + (size_t)(h * HD + l31) * NN
                       + z * ZT + sst * 32 + sfc * 16 + hi * 8;

    // prologue: tile 0 into staging regs
    bf16x8 kreg = *(const bf16x8*)(gk);
    bf16x8 vreg = *(const bf16x8*)(gv);

    for (int it = 0; it < NIT; ++it) {
        const int b = it & 1;
        // commit staged tile to LDS (lane-linear, conflict-free)
        *(bf16x8*)(&Ks[b][w * 512 + lane * 8]) = kreg;
        *(bf16x8*)(&Vs[b][w * 512 + lane * 8]) = vreg;
        __syncthreads();   // writes visible before reads; only barrier needed

        // issue next tile's loads; consumed only at next iteration's
        // ds_write (opposite buffer), so compute hides the latency
        if (it + 1 < NIT) {
            kreg = *(const bf16x8*)(gk + (size_t)(it + 1) * 64 * C);
            vreg = *(const bf16x8*)(gv + (it + 1) * 64);
        }

        const u16* KsB = Ks[b];
        const u16* VsB = Vs[b];
        #pragma unroll
        for (int s = 0; s < 2; ++s) {
            const bf16x8 kf0 = *(const bf16x8*)(KsB + (s * 2 + 0) * 512 + lane * 8);
            const bf16x8 kf1 = *(const bf16x8*)(KsB + (s * 2 + 1) * 512 + lane * 8);
            const bf16x8 vf0 = *(const bf16x8*)(VsB + (s * 2 + 0) * 512 + lane * 8);
            const bf16x8 vf1 = *(const bf16x8*)(VsB + (s * 2 + 1) * 512 + lane * 8);

            // group A: QK^T (S^T = K Q^T), softmax, PV
            f32x16 sA = zero16();
            sA = __builtin_amdgcn_mfma_f32_32x32x16_bf16(kf0, qf0a, sA, 0, 0, 0);
            sA = __builtin_amdgcn_mfma_f32_32x32x16_bf16(kf1, qf1a, sA, 0, 0, 0);
            const bf16x8 paA0 = softmax_chunk<0>(sA, lsA);
            oA = __builtin_amdgcn_mfma_f32_32x32x16_bf16(paA0, vf0, oA, 0, 0, 0);
            const bf16x8 paA1 = softmax_chunk<1>(sA, lsA);
            oA = __builtin_amdgcn_mfma_f32_32x32x16_bf16(paA1, vf1, oA, 0, 0, 0);

            // group B
            f32x16 sB = zero16();
            sB = __builtin_amdgcn_mfma_f32_32x32x16_bf16(kf0, qf0b, sB, 0, 0, 0);
            sB = __builtin_amdgcn_mfma_f32_32x32x16_bf16(kf1, qf1b, sB, 0, 0, 0);
            const bf16x8 paB0 = softmax_chunk<0>(sB, lsB);
            oB = __builtin_amdgcn_mfma_f32_32x32x16_bf16(paB0, vf0, oB, 0, 0, 0);
            const bf16x8 paB1 = softmax_chunk<1>(sB, lsB);
            oB = __builtin_amdgcn_mfma_f32_32x32x16_bf16(paB1, vf1, oB, 0, 0, 0);
        }
    }

    // lane's lsum covers 16 j per tile; xor-32 adds the partner half.
    lsA += __shfl_xor(lsA, 32);
    lsB += __shfl_xor(lsB, 32);
    if (hi == 0) {
        lp[((size_t)z * NH + h) * NN + qbase + l31] = lsA;
        lp[((size_t)z * NH + h) * NN + qbase + 32 + l31] = lsB;
    }

    #pragma unroll
    for (int r = 0; r < 16; ++r) {
        const int qrA = qbase + (r & 3) + 8 * (r >> 2) + 4 * hi;
        msgp[((size_t)z * NN + qrA) * C + h * HD + l31] = oA[r];
        msgp[((size_t)z * NN + qrA + 32) * C + h * HD + l31] = oB[r];
    }
}

// ---------------------------------------------------------------------------
// Kernel 3: reduce z-partials, y = x + (msg/l) @ Wo + bo, LayerNorm.
// 16-row tiles (ALL MFMA rows used), 256 blocks.
// ---------------------------------------------------------------------------
#define OROWS 16
__global__ __launch_bounds__(256) void out_ln_mfma_kernel(
    const float* __restrict__ msgp, const float* __restrict__ lp,
    const u16* __restrict__ WoT, const float* __restrict__ bo,
    const float* __restrict__ x, const float* __restrict__ gamma,
    const float* __restrict__ beta, float* __restrict__ out)
{
    __shared__ float sums[2][4][OROWS];
    const int m0 = blockIdx.x * OROWS;
    const int t = threadIdx.x;
    const int w = t >> 6, lane = t & 63;
    const int l16 = lane & 15, quad = lane >> 4;

    f32x4 acc[4];
    #pragma unroll
    for (int ct = 0; ct < 4; ++ct) acc[ct] = f32x4{0.f, 0.f, 0.f, 0.f};

    const int ar = m0 + l16;   // exact: 256 blocks x 16 rows = NN
    #pragma unroll
    for (int kk = 0; kk < 8; ++kk) {
        float l = 0.f;
        #pragma unroll
        for (int z = 0; z < NZ; ++z)
            l += lp[((size_t)z * NH + kk) * NN + ar];
        const float li = 1.f / l;

        float4 a0 = float4{0.f, 0.f, 0.f, 0.f};
        float4 a1 = float4{0.f, 0.f, 0.f, 0.f};
        #pragma unroll
        for (int z = 0; z < NZ; ++z) {
            const float* arow = msgp + ((size_t)z * NN + ar) * C;
            const float4 b0 = *(const float4*)(arow + kk * 32 + quad * 8);
            const float4 b1 = *(const float4*)(arow + kk * 32 + quad * 8 + 4);
            a0.x += b0.x; a0.y += b0.y; a0.z += b0.z; a0.w += b0.w;
            a1.x += b1.x; a1.y += b1.y; a1.z += b1.z; a1.w += b1.w;
        }

        union { __hip_bfloat162 h2[4]; bf16x8 v; } af;
        af.h2[0] = __float22bfloat162_rn(float2{a0.x * li, a0.y * li});
        af.h2[1] = __float22bfloat162_rn(float2{a0.z * li, a0.w * li});
        af.h2[2] = __float22bfloat162_rn(float2{a1.x * li, a1.y * li});
        af.h2[3] = __float22bfloat162_rn(float2{a1.z * li, a1.w * li});
        #pragma unroll
        for (int ct = 0; ct < 4; ++ct) {
            const bf16x8 bfr = *(const bf16x8*)(
                WoT + (size_t)(w * 64 + ct * 16 + l16) * C + kk * 32 + quad * 8);
            acc[ct] = __builtin_amdgcn_mfma_f32_16x16x32_bf16(af.v, bfr, acc[ct], 0, 0, 0);
        }
    }

    float val[4][4];
    #pragma unroll
    for (int r = 0; r < 4; ++r) {
        const int row = m0 + quad * 4 + r;
        float sr = 0.f, qr = 0.f;
        #pragma unroll
        for (int ct = 0; ct < 4; ++ct) {
            const int c = w * 64 + ct * 16 + l16;
            const float v = acc[ct][r] + bo[c] + x[(size_t)row * C + c];
            val[ct][r] = v;
            sr += v;
            qr = fmaf(v, v, qr);
        }
        sr += __shfl_xor(sr, 1); sr += __shfl_xor(sr, 2);
        sr += __shfl_xor(sr, 4); sr += __shfl_xor(sr, 8);
        qr += __shfl_xor(qr, 1); qr += __shfl_xor(qr, 2);
        qr += __shfl_xor(qr, 4); qr += __shfl_xor(qr, 8);
        if (l16 == 0) {
            sums[0][w][quad * 4 + r] = sr;
            sums[1][w][quad * 4 + r] = qr;
        }
    }
    __syncthreads();

    #pragma unroll
    for (int r = 0; r < 4; ++r) {
        const int ri = quad * 4 + r;
        const int row = m0 + ri;
        const float tot  = sums[0][0][ri] + sums[0][1][ri] + sums[0][2][ri] + sums[0][3][ri];
        const float tot2 = sums[1][0][ri] + sums[1][1][ri] + sums[1][2][ri] + sums[1][3][ri];
        const float mu = tot * (1.f / C);
        const float var = fmaxf(tot2 * (1.f / C) - mu * mu, 0.f);
        const float rstd = rsqrtf(var + LN_EPS);
        #pragma unroll
        for (int ct = 0; ct < 4; ++ct) {
            const int c = w * 64 + ct * 16 + l16;
            out[(size_t)row * C + c] = (val[ct][r] - mu) * rstd * gamma[c] + beta[c];
        }
    }
}

// ---------------------------------------------------------------------------
extern "C" void kernel_launch(void* const* d_in, const int* in_sizes, int n_in,
                              void* d_out, int out_size, void* d_ws, size_t ws_size,
                              hipStream_t stream) {
    const float* x     = (const float*)d_in[0];
    const float* Wq    = (const float*)d_in[1];
    const float* bq    = (const float*)d_in[2];
    const float* Wk    = (const float*)d_in[3];
    const float* bk    = (const float*)d_in[4];
    const float* Wv    = (const float*)d_in[5];
    const float* bv    = (const float*)d_in[6];
    const float* scale = (const float*)d_in[7];
    const float* Wo    = (const float*)d_in[8];
    const float* bo    = (const float*)d_in[9];
    const float* gamma = (const float*)d_in[10];
    const float* beta  = (const float*)d_in[11];
    float* out = (float*)d_out;

    u16* qb     = (u16*)d_ws;                              // 2 MB
    u16* kb     = qb + (size_t)NN * C;                     // 2 MB
    u16* vT     = kb + (size_t)NN * C;                     // 2 MB
    u16* WqkvT  = vT + (size_t)NN * C;                     // 384 KB
    u16* WoT    = WqkvT + (size_t)3 * C * C;               // 128 KB
    float* msgp = (float*)(WoT + (size_t)C * C);           // NZ*4 MB = 16 MB
    float* lp   = msgp + (size_t)NZ * NN * C;              // 512 KB

    prep_kernel<<<dim3(8, 8, 4), 256, 0, stream>>>(Wq, Wk, Wv, Wo,
                                                   WqkvT, WoT);
    qkv_mfma_kernel<<<dim3(NN / 64, 12), 256, 0, stream>>>(
        x, WqkvT, bq, bk, bv, scale, qb, kb, vT);
    attn_mfma_kernel<<<dim3(NN / TQB, NH, NZ), 256, 0, stream>>>(
        qb, kb, vT, msgp, lp);
    out_ln_mfma_kernel<<<NN / OROWS, 256, 0, stream>>>(msgp, lp, WoT, bo, x,
                                                       gamma, beta, out);
}

// Round 8
// 144.612 us; speedup vs baseline: 1.3005x; 1.0038x over previous
//
#include <hip/hip_runtime.h>
#include <hip/hip_bf16.h>
#include <math.h>

#define NN 4096      // nodes
#define C  256       // feature dim
#define NH 8         // heads
#define HD 32        // head dim
#define LN_EPS 1e-5f
#define LOG2E 1.44269504088896340736f

#define NZ 2               // key-split factor (partial buffers, no atomics)
#define ZT (NN / NZ)       // 2048 keys per z-slice
#define TQB 256            // q rows per block (64 per wave, 2 groups of 32)
#define NIT (ZT / 64)      // 32 tiles of 64 keys

typedef unsigned short u16;
typedef __attribute__((ext_vector_type(8))) short bf16x8;
typedef __attribute__((ext_vector_type(4))) float f32x4;
typedef __attribute__((ext_vector_type(16))) float f32x16;

__device__ inline u16 f2b(float f) {
    union { float f; unsigned u; } v; v.f = f;
    unsigned r = (v.u + 0x7fff + ((v.u >> 16) & 1)) >> 16;  // RNE
    return (u16)r;
}

__device__ inline float fexp2(float x) {
#if __has_builtin(__builtin_amdgcn_exp2f)
    return __builtin_amdgcn_exp2f(x);      // single v_exp_f32
#else
    return exp2f(x);
#endif
}

// pack bf16(e0)|bf16(e1)<<16 by truncation: ONE v_perm_b32
__device__ inline unsigned pack_trunc(float e0, float e1) {
    return __builtin_amdgcn_perm(__float_as_uint(e1), __float_as_uint(e0),
                                 0x07060302u);
}

__device__ inline f32x16 zero16() {
    return f32x16{0.f,0.f,0.f,0.f, 0.f,0.f,0.f,0.f,
                  0.f,0.f,0.f,0.f, 0.f,0.f,0.f,0.f};
}

// exp2 + bf16-pack + permlane32_swap: turns S^T chunk c (16 j per lane) into
// the PV A-fragment; accumulates row-sum of exps. Verified layout (round 1).
template<int c>
__device__ inline bf16x8 softmax_chunk(const f32x16 s, float& lsum) {
    const float e0 = fexp2(s[8*c+0]);
    const float e1 = fexp2(s[8*c+1]);
    const float e2 = fexp2(s[8*c+2]);
    const float e3 = fexp2(s[8*c+3]);
    const float e4 = fexp2(s[8*c+4]);
    const float e5 = fexp2(s[8*c+5]);
    const float e6 = fexp2(s[8*c+6]);
    const float e7 = fexp2(s[8*c+7]);
    lsum += ((e0 + e1) + (e2 + e3)) + ((e4 + e5) + (e6 + e7));
    const unsigned p01 = pack_trunc(e0, e1);
    const unsigned p23 = pack_trunc(e2, e3);
    const unsigned p45 = pack_trunc(e4, e5);
    const unsigned p67 = pack_trunc(e6, e7);
    const auto w02 = __builtin_amdgcn_permlane32_swap(p01, p45, false, false);
    const auto w13 = __builtin_amdgcn_permlane32_swap(p23, p67, false, false);
    union { unsigned w[4]; bf16x8 v; } pa;
    pa.w[0] = w02[0]; pa.w[1] = w13[0];
    pa.w[2] = w02[1]; pa.w[3] = w13[1];
    return pa.v;
}

// ---------------------------------------------------------------------------
// Kernel 0: prep — weight transpose + bf16 (WqkvT=[Wq^T|Wk^T|Wv^T], WoT).
// grid (8,8,4), block 256.
// ---------------------------------------------------------------------------
__global__ __launch_bounds__(256) void prep_kernel(
    const float* __restrict__ Wq, const float* __restrict__ Wk,
    const float* __restrict__ Wv, const float* __restrict__ Wo,
    u16* __restrict__ WqkvT, u16* __restrict__ WoT)
{
    __shared__ float tile[32][33];
    const int z = blockIdx.z;
    const float* W = (z == 0) ? Wq : (z == 1) ? Wk : (z == 2) ? Wv : Wo;
    u16* WT = (z == 3) ? WoT : (WqkvT + (size_t)z * 256 * 256);
    const int tx = threadIdx.x & 31, ty = threadIdx.x >> 5;
    const int n0 = blockIdx.x * 32, k0 = blockIdx.y * 32;
    #pragma unroll
    for (int i = 0; i < 32; i += 8)
        tile[ty + i][tx] = W[(size_t)(k0 + ty + i) * 256 + n0 + tx];
    __syncthreads();
    #pragma unroll
    for (int i = 0; i < 32; i += 8)
        WT[(size_t)(n0 + ty + i) * 256 + k0 + tx] = f2b(tile[tx][ty + i]);
}

// ---------------------------------------------------------------------------
// Kernel 1: QKV projection via MFMA (64x64 tiles, 4 waves). A-frag built
// directly from f32 x (2x float4 + RNE cvt). qb pre-scaled by scale*log2e;
// v emitted as V^T.
// ---------------------------------------------------------------------------
__global__ __launch_bounds__(256) void qkv_mfma_kernel(
    const float* __restrict__ x, const u16* __restrict__ WT,
    const float* __restrict__ bq, const float* __restrict__ bk,
    const float* __restrict__ bv, const float* __restrict__ scale_p,
    u16* __restrict__ qb, u16* __restrict__ kb, u16* __restrict__ vT)
{
    const int m0 = blockIdx.x * 64;
    const int n0 = blockIdx.y * 64;
    const int t = threadIdx.x;
    const int wave = t >> 6, lane = t & 63;
    const int l16 = lane & 15, quad = lane >> 4;

    f32x4 acc[4];
    #pragma unroll
    for (int ct = 0; ct < 4; ++ct) acc[ct] = f32x4{0.f, 0.f, 0.f, 0.f};

    const float* xrow = x + (size_t)(m0 + wave * 16 + l16) * C;
    #pragma unroll
    for (int kk = 0; kk < 8; ++kk) {
        const float4 a0 = *(const float4*)(xrow + kk * 32 + quad * 8);
        const float4 a1 = *(const float4*)(xrow + kk * 32 + quad * 8 + 4);
        union { __hip_bfloat162 h2[4]; bf16x8 v; } af;
        af.h2[0] = __float22bfloat162_rn(float2{a0.x, a0.y});
        af.h2[1] = __float22bfloat162_rn(float2{a0.z, a0.w});
        af.h2[2] = __float22bfloat162_rn(float2{a1.x, a1.y});
        af.h2[3] = __float22bfloat162_rn(float2{a1.z, a1.w});
        #pragma unroll
        for (int ct = 0; ct < 4; ++ct) {
            const bf16x8 bfr = *(const bf16x8*)(
                WT + (size_t)(n0 + ct * 16 + l16) * C + kk * 32 + quad * 8);
            acc[ct] = __builtin_amdgcn_mfma_f32_16x16x32_bf16(af.v, bfr, acc[ct], 0, 0, 0);
        }
    }

    const int sect = n0 >> 8;
    const int c0 = n0 & 255;
    const int rbase = m0 + wave * 16 + quad * 4;
    if (sect == 0) {
        const float scl = (*scale_p) * LOG2E;
        #pragma unroll
        for (int ct = 0; ct < 4; ++ct) {
            const int c = c0 + ct * 16 + l16;
            const float b = bq[c];
            #pragma unroll
            for (int r = 0; r < 4; ++r)
                qb[(size_t)(rbase + r) * C + c] = f2b((acc[ct][r] + b) * scl);
        }
    } else if (sect == 1) {
        #pragma unroll
        for (int ct = 0; ct < 4; ++ct) {
            const int c = c0 + ct * 16 + l16;
            const float b = bk[c];
            #pragma unroll
            for (int r = 0; r < 4; ++r)
                kb[(size_t)(rbase + r) * C + c] = f2b(acc[ct][r] + b);
        }
    } else {
        #pragma unroll
        for (int ct = 0; ct < 4; ++ct) {
            const int c = c0 + ct * 16 + l16;
            const float b = bv[c];
            union { u16 u[4]; unsigned long long ull; } pk;
            #pragma unroll
            for (int r = 0; r < 4; ++r) pk.u[r] = f2b(acc[ct][r] + b);
            *(unsigned long long*)(vT + (size_t)c * NN + rbase) = pk.ull;
        }
    }
}

// ---------------------------------------------------------------------------
// Kernel 2: MFMA attention. 32x32x16, swapped QK^T, register-P via
// pack_trunc + permlane32_swap. K/V tiles staged in frag-order LDS
// (lane-linear b128, conflict-free), register-staged double buffer with a
// SINGLE barrier per tile. Dual Q-groups per wave (64 q-rows): every K/V
// fragment feeds 2 Q-frags. NO ATOMICS: plain coalesced stores of z-slice
// partial O and l. grid (16, 8, 2), 4 waves (1 block/CU).
// ---------------------------------------------------------------------------
__global__ __launch_bounds__(256) void attn_mfma_kernel(
    const u16* __restrict__ q, const u16* __restrict__ k,
    const u16* __restrict__ vT, float* __restrict__ msgp,
    float* __restrict__ lp)
{
    // frag-order tiles: 4 frags x 64 lanes x 8 u16 = 2048 u16 = 4KB each
    __shared__ u16 Ks[2][2048];
    __shared__ u16 Vs[2][2048];

    const int h = blockIdx.y, z = blockIdx.z;
    const int t = threadIdx.x;
    const int w = t >> 6, lane = t & 63;
    const int l31 = lane & 31, hi = lane >> 5;
    const int qbase = blockIdx.x * TQB + w * 64;

    // Q B-frags for two 32-row groups: lane holds Q[q][d = hi*8+e (+16)]
    const u16* qrpA = q + (size_t)(qbase + l31) * C + h * HD + hi * 8;
    const bf16x8 qf0a = *(const bf16x8*)(qrpA);
    const bf16x8 qf1a = *(const bf16x8*)(qrpA + 16);
    const u16* qrpB = qrpA + 32 * C;
    const bf16x8 qf0b = *(const bf16x8*)(qrpB);
    const bf16x8 qf1b = *(const bf16x8*)(qrpB + 16);

    f32x16 oA = zero16(), oB = zero16();
    float lsA = 0.f, lsB = 0.f;

    // wave w stages fragment w: K[j-sub sst*32 + l31][col sfc*16 + hi*8],
    // vT[d = l31][j-sub sst*32 + sfc*16 + hi*8]
    const int sst = w >> 1, sfc = w & 1;
    const u16* gk = k + (size_t)(z * ZT + sst * 32 + l31) * C
                      + h * HD + sfc * 16 + hi * 8;
    const u16* gv = vT + (size_t)(h * HD + l31) * NN
                       + z * ZT + sst * 32 + sfc * 16 + hi * 8;

    // prologue: tile 0 into staging regs
    bf16x8 kreg = *(const bf16x8*)(gk);
    bf16x8 vreg = *(const bf16x8*)(gv);

    for (int it = 0; it < NIT; ++it) {
        const int b = it & 1;
        // commit staged tile to LDS (lane-linear, conflict-free)
        *(bf16x8*)(&Ks[b][w * 512 + lane * 8]) = kreg;
        *(bf16x8*)(&Vs[b][w * 512 + lane * 8]) = vreg;
        __syncthreads();   // writes visible before reads; only barrier needed

        // issue next tile's loads; consumed only at next iteration's
        // ds_write (opposite buffer), so compute hides the latency
        if (it + 1 < NIT) {
            kreg = *(const bf16x8*)(gk + (size_t)(it + 1) * 64 * C);
            vreg = *(const bf16x8*)(gv + (it + 1) * 64);
        }

        const u16* KsB = Ks[b];
        const u16* VsB = Vs[b];
        #pragma unroll
        for (int s = 0; s < 2; ++s) {
            const bf16x8 kf0 = *(const bf16x8*)(KsB + (s * 2 + 0) * 512 + lane * 8);
            const bf16x8 kf1 = *(const bf16x8*)(KsB + (s * 2 + 1) * 512 + lane * 8);
            const bf16x8 vf0 = *(const bf16x8*)(VsB + (s * 2 + 0) * 512 + lane * 8);
            const bf16x8 vf1 = *(const bf16x8*)(VsB + (s * 2 + 1) * 512 + lane * 8);

            // group A: QK^T (S^T = K Q^T), softmax, PV
            f32x16 sA = zero16();
            sA = __builtin_amdgcn_mfma_f32_32x32x16_bf16(kf0, qf0a, sA, 0, 0, 0);
            sA = __builtin_amdgcn_mfma_f32_32x32x16_bf16(kf1, qf1a, sA, 0, 0, 0);
            const bf16x8 paA0 = softmax_chunk<0>(sA, lsA);
            oA = __builtin_amdgcn_mfma_f32_32x32x16_bf16(paA0, vf0, oA, 0, 0, 0);
            const bf16x8 paA1 = softmax_chunk<1>(sA, lsA);
            oA = __builtin_amdgcn_mfma_f32_32x32x16_bf16(paA1, vf1, oA, 0, 0, 0);

            // group B
            f32x16 sB = zero16();
            sB = __builtin_amdgcn_mfma_f32_32x32x16_bf16(kf0, qf0b, sB, 0, 0, 0);
            sB = __builtin_amdgcn_mfma_f32_32x32x16_bf16(kf1, qf1b, sB, 0, 0, 0);
            const bf16x8 paB0 = softmax_chunk<0>(sB, lsB);
            oB = __builtin_amdgcn_mfma_f32_32x32x16_bf16(paB0, vf0, oB, 0, 0, 0);
            const bf16x8 paB1 = softmax_chunk<1>(sB, lsB);
            oB = __builtin_amdgcn_mfma_f32_32x32x16_bf16(paB1, vf1, oB, 0, 0, 0);
        }
    }

    // lane's lsum covers 16 j per tile; xor-32 adds the partner half.
    lsA += __shfl_xor(lsA, 32);
    lsB += __shfl_xor(lsB, 32);
    if (hi == 0) {
        lp[((size_t)z * NH + h) * NN + qbase + l31] = lsA;
        lp[((size_t)z * NH + h) * NN + qbase + 32 + l31] = lsB;
    }

    #pragma unroll
    for (int r = 0; r < 16; ++r) {
        const int qrA = qbase + (r & 3) + 8 * (r >> 2) + 4 * hi;
        msgp[((size_t)z * NN + qrA) * C + h * HD + l31] = oA[r];
        msgp[((size_t)z * NN + qrA + 32) * C + h * HD + l31] = oB[r];
    }
}

// ---------------------------------------------------------------------------
// Kernel 3: reduce z-partials, y = x + (msg/l) @ Wo + bo, LayerNorm.
// 16-row tiles (ALL MFMA rows used), 256 blocks.
// ---------------------------------------------------------------------------
#define OROWS 16
__global__ __launch_bounds__(256) void out_ln_mfma_kernel(
    const float* __restrict__ msgp, const float* __restrict__ lp,
    const u16* __restrict__ WoT, const float* __restrict__ bo,
    const float* __restrict__ x, const float* __restrict__ gamma,
    const float* __restrict__ beta, float* __restrict__ out)
{
    __shared__ float sums[2][4][OROWS];
    const int m0 = blockIdx.x * OROWS;
    const int t = threadIdx.x;
    const int w = t >> 6, lane = t & 63;
    const int l16 = lane & 15, quad = lane >> 4;

    f32x4 acc[4];
    #pragma unroll
    for (int ct = 0; ct < 4; ++ct) acc[ct] = f32x4{0.f, 0.f, 0.f, 0.f};

    const int ar = m0 + l16;   // exact: 256 blocks x 16 rows = NN
    #pragma unroll
    for (int kk = 0; kk < 8; ++kk) {
        float l = 0.f;
        #pragma unroll
        for (int z = 0; z < NZ; ++z)
            l += lp[((size_t)z * NH + kk) * NN + ar];
        const float li = 1.f / l;

        float4 a0 = float4{0.f, 0.f, 0.f, 0.f};
        float4 a1 = float4{0.f, 0.f, 0.f, 0.f};
        #pragma unroll
        for (int z = 0; z < NZ; ++z) {
            const float* arow = msgp + ((size_t)z * NN + ar) * C;
            const float4 b0 = *(const float4*)(arow + kk * 32 + quad * 8);
            const float4 b1 = *(const float4*)(arow + kk * 32 + quad * 8 + 4);
            a0.x += b0.x; a0.y += b0.y; a0.z += b0.z; a0.w += b0.w;
            a1.x += b1.x; a1.y += b1.y; a1.z += b1.z; a1.w += b1.w;
        }

        union { __hip_bfloat162 h2[4]; bf16x8 v; } af;
        af.h2[0] = __float22bfloat162_rn(float2{a0.x * li, a0.y * li});
        af.h2[1] = __float22bfloat162_rn(float2{a0.z * li, a0.w * li});
        af.h2[2] = __float22bfloat162_rn(float2{a1.x * li, a1.y * li});
        af.h2[3] = __float22bfloat162_rn(float2{a1.z * li, a1.w * li});
        #pragma unroll
        for (int ct = 0; ct < 4; ++ct) {
            const bf16x8 bfr = *(const bf16x8*)(
                WoT + (size_t)(w * 64 + ct * 16 + l16) * C + kk * 32 + quad * 8);
            acc[ct] = __builtin_amdgcn_mfma_f32_16x16x32_bf16(af.v, bfr, acc[ct], 0, 0, 0);
        }
    }

    float val[4][4];
    #pragma unroll
    for (int r = 0; r < 4; ++r) {
        const int row = m0 + quad * 4 + r;
        float sr = 0.f, qr = 0.f;
        #pragma unroll
        for (int ct = 0; ct < 4; ++ct) {
            const int c = w * 64 + ct * 16 + l16;
            const float v = acc[ct][r] + bo[c] + x[(size_t)row * C + c];
            val[ct][r] = v;
            sr += v;
            qr = fmaf(v, v, qr);
        }
        sr += __shfl_xor(sr, 1); sr += __shfl_xor(sr, 2);
        sr += __shfl_xor(sr, 4); sr += __shfl_xor(sr, 8);
        qr += __shfl_xor(qr, 1); qr += __shfl_xor(qr, 2);
        qr += __shfl_xor(qr, 4); qr += __shfl_xor(qr, 8);
        if (l16 == 0) {
            sums[0][w][quad * 4 + r] = sr;
            sums[1][w][quad * 4 + r] = qr;
        }
    }
    __syncthreads();

    #pragma unroll
    for (int r = 0; r < 4; ++r) {
        const int ri = quad * 4 + r;
        const int row = m0 + ri;
        const float tot  = sums[0][0][ri] + sums[0][1][ri] + sums[0][2][ri] + sums[0][3][ri];
        const float tot2 = sums[1][0][ri] + sums[1][1][ri] + sums[1][2][ri] + sums[1][3][ri];
        const float mu = tot * (1.f / C);
        const float var = fmaxf(tot2 * (1.f / C) - mu * mu, 0.f);
        const float rstd = rsqrtf(var + LN_EPS);
        #pragma unroll
        for (int ct = 0; ct < 4; ++ct) {
            const int c = w * 64 + ct * 16 + l16;
            out[(size_t)row * C + c] = (val[ct][r] - mu) * rstd * gamma[c] + beta[c];
        }
    }
}

// ---------------------------------------------------------------------------
extern "C" void kernel_launch(void* const* d_in, const int* in_sizes, int n_in,
                              void* d_out, int out_size, void* d_ws, size_t ws_size,
                              hipStream_t stream) {
    const float* x     = (const float*)d_in[0];
    const float* Wq    = (const float*)d_in[1];
    const float* bq    = (const float*)d_in[2];
    const float* Wk    = (const float*)d_in[3];
    const float* bk    = (const float*)d_in[4];
    const float* Wv    = (const float*)d_in[5];
    const float* bv    = (const float*)d_in[6];
    const float* scale = (const float*)d_in[7];
    const float* Wo    = (const float*)d_in[8];
    const float* bo    = (const float*)d_in[9];
    const float* gamma = (const float*)d_in[10];
    const float* beta  = (const float*)d_in[11];
    float* out = (float*)d_out;

    u16* qb     = (u16*)d_ws;                              // 2 MB
    u16* kb     = qb + (size_t)NN * C;                     // 2 MB
    u16* vT     = kb + (size_t)NN * C;                     // 2 MB
    u16* WqkvT  = vT + (size_t)NN * C;                     // 384 KB
    u16* WoT    = WqkvT + (size_t)3 * C * C;               // 128 KB
    float* msgp = (float*)(WoT + (size_t)C * C);           // NZ*4 MB = 8 MB
    float* lp   = msgp + (size_t)NZ * NN * C;              // 256 KB

    prep_kernel<<<dim3(8, 8, 4), 256, 0, stream>>>(Wq, Wk, Wv, Wo,
                                                   WqkvT, WoT);
    qkv_mfma_kernel<<<dim3(NN / 64, 12), 256, 0, stream>>>(
        x, WqkvT, bq, bk, bv, scale, qb, kb, vT);
    attn_mfma_kernel<<<dim3(NN / TQB, NH, NZ), 256, 0, stream>>>(
        qb, kb, vT, msgp, lp);
    out_ln_mfma_kernel<<<NN / OROWS, 256, 0, stream>>>(msgp, lp, WoT, bo, x,
                                                       gamma, beta, out);
}